// Round 1
// baseline (637.698 us; speedup 1.0000x reference)
//
#include <hip/hip_runtime.h>
#include <hip/hip_bf16.h>
#include <cstdint>
#include <cstddef>

// ---------------------------------------------------------------------------
// PrefillDecoderLayer on MI355X (gfx950).
// Strategy: fp32 residual stream; all GEMMs via bf16 MFMA 16x16x32 (m97-style
// 128x128 tiles + global_load_lds width=16); flash attention (64-row Q tiles,
// online softmax) for SA (causal) and XA (encoder mask).
// ---------------------------------------------------------------------------

typedef __attribute__((ext_vector_type(4))) float f32x4;
typedef __attribute__((ext_vector_type(8))) short s8v;   // 8 bf16 as raw bits

#define DEVI __device__ __forceinline__

DEVI short f2bf(float f) {  // RNE float -> bf16 bits
  union { float f; unsigned u; } x; x.f = f;
  unsigned r = x.u + 0x7fffu + ((x.u >> 16) & 1u);
  return (short)(r >> 16);
}
DEVI float bf2f(short s) {
  union { unsigned u; float f; } x; x.u = ((unsigned)(unsigned short)s) << 16;
  return x.f;
}
DEVI void gload_lds16(const void* g, void* l) {
  __builtin_amdgcn_global_load_lds((const __attribute__((address_space(1))) void*)g,
                                   (__attribute__((address_space(3))) void*)l,
                                   16, 0, 0);
}

// ---------------------------------------------------------------------------
// Weight transpose + fp32->bf16:  w[K][N] f32  ->  wt[N][K] bf16
// K,N multiples of 32 for all weights here.
// ---------------------------------------------------------------------------
__global__ __launch_bounds__(256) void k_transpose_cvt(
    const float* __restrict__ w, short* __restrict__ wt, int K, int N) {
  __shared__ float tile[32][33];
  int n0 = blockIdx.x * 32, k0 = blockIdx.y * 32;
  int tx = threadIdx.x & 31, ty = threadIdx.x >> 5;  // ty 0..7
#pragma unroll
  for (int i = 0; i < 32; i += 8)
    tile[ty + i][tx] = w[(size_t)(k0 + ty + i) * N + n0 + tx];
  __syncthreads();
#pragma unroll
  for (int i = 0; i < 32; i += 8)
    wt[(size_t)(n0 + ty + i) * K + k0 + tx] = f2bf(tile[tx][ty + i]);
}

// ---------------------------------------------------------------------------
// LayerNorm over D=1024, fp32 in -> bf16 out. One block (256 thr) per row.
// ---------------------------------------------------------------------------
__global__ __launch_bounds__(256) void k_ln(
    const float* __restrict__ x, const float* __restrict__ g,
    short* __restrict__ out) {
  int row = blockIdx.x;
  const float* xr = x + (size_t)row * 1024;
  int t = threadIdx.x, wid = t >> 6, lane = t & 63;
  float v[4]; float s = 0.f;
#pragma unroll
  for (int i = 0; i < 4; i++) { v[i] = xr[t + i * 256]; s += v[i]; }
#pragma unroll
  for (int m = 32; m >= 1; m >>= 1) s += __shfl_xor(s, m);
  __shared__ float red[4];
  if (lane == 0) red[wid] = s;
  __syncthreads();
  float mean = (red[0] + red[1] + red[2] + red[3]) * (1.f / 1024.f);
  float q = 0.f;
#pragma unroll
  for (int i = 0; i < 4; i++) { v[i] -= mean; q += v[i] * v[i]; }
#pragma unroll
  for (int m = 32; m >= 1; m >>= 1) q += __shfl_xor(q, m);
  __syncthreads();
  if (lane == 0) red[wid] = q;
  __syncthreads();
  float var = (red[0] + red[1] + red[2] + red[3]) * (1.f / 1024.f);
  float rs = rsqrtf(var + 1e-5f);
  short* orow = out + (size_t)row * 1024;
#pragma unroll
  for (int i = 0; i < 4; i++) orow[t + i * 256] = f2bf(v[i] * rs * g[t + i * 256]);
}

// ---------------------------------------------------------------------------
// GEMM: C[M][N] = A[M][K](bf16) @ Bt[N][K](bf16)^T  (+res, gelu, f32/bf16 out)
// 128x128 tile, BK=32, 4 waves (2x2), each wave 64x64 via 4x4 mfma 16x16x32.
// ---------------------------------------------------------------------------
template <bool RES, bool GELU_, bool F32OUT, bool BF16OUT>
__global__ __launch_bounds__(256) void k_gemm(
    const short* __restrict__ A, const short* __restrict__ Bt,
    float* __restrict__ Cf, short* __restrict__ Cb,
    const float* __restrict__ res, int M, int N, int K) {
  __shared__ short As[128 * 32];
  __shared__ short Bs[128 * 32];
  int t = threadIdx.x, wid = t >> 6, lane = t & 63;
  int la = lane & 15, lb = lane >> 4;
  int wr = wid >> 1, wc = wid & 1;
  int am = blockIdx.x * 128, bn = blockIdx.y * 128;

  f32x4 acc[4][4];
#pragma unroll
  for (int m = 0; m < 4; m++)
#pragma unroll
    for (int n = 0; n < 4; n++) acc[m][n] = (f32x4){0.f, 0.f, 0.f, 0.f};

  for (int k0 = 0; k0 < K; k0 += 32) {
#pragma unroll
    for (int i = 0; i < 2; i++) {
      int fl = i * 256 + t;
      int r = fl >> 2, c = (fl & 3) << 3;
      int ar = am + r; if (ar > M - 1) ar = M - 1;  // clamp for M=6000
      gload_lds16(A + (size_t)ar * K + k0 + c, As + (size_t)(i * 256 + wid * 64) * 8);
      int br = bn + r;  // N always multiple of 128
      gload_lds16(Bt + (size_t)br * K + k0 + c, Bs + (size_t)(i * 256 + wid * 64) * 8);
    }
    __syncthreads();
    s8v af[4], bfg[4];
#pragma unroll
    for (int m = 0; m < 4; m++)
      af[m] = *(const s8v*)(As + (wr * 64 + m * 16 + la) * 32 + lb * 8);
#pragma unroll
    for (int n = 0; n < 4; n++)
      bfg[n] = *(const s8v*)(Bs + (wc * 64 + n * 16 + la) * 32 + lb * 8);
#pragma unroll
    for (int m = 0; m < 4; m++)
#pragma unroll
      for (int n = 0; n < 4; n++)
        acc[m][n] = __builtin_amdgcn_mfma_f32_16x16x32_bf16(af[m], bfg[n], acc[m][n], 0, 0, 0);
    __syncthreads();
  }

#pragma unroll
  for (int m = 0; m < 4; m++) {
    int rb = am + wr * 64 + m * 16 + lb * 4;
#pragma unroll
    for (int n = 0; n < 4; n++) {
      int col = bn + wc * 64 + n * 16 + la;
#pragma unroll
      for (int j = 0; j < 4; j++) {
        int r = rb + j;
        if (r < M) {
          float v = acc[m][n][j];
          if (RES) v += res[(size_t)r * N + col];
          if (GELU_) {
            float u = v;
            v = 0.5f * u * (1.f + tanhf(0.7978845608028654f * (u + 0.044715f * u * u * u)));
          }
          if (F32OUT) Cf[(size_t)r * N + col] = v;
          if (BF16OUT) Cb[(size_t)r * N + col] = f2bf(v);
        }
      }
    }
  }
}

// ---------------------------------------------------------------------------
// Flash attention. Grid: (Tq/64, B*H). 4 waves x 16 q-rows. 64-key tiles.
// q/k/v consumed in-place from GEMM outputs via row strides; D_HEAD=64.
// ---------------------------------------------------------------------------
template <bool CAUSAL>
__global__ __launch_bounds__(256) void k_attn(
    const short* __restrict__ qbuf, int qrs,
    const short* __restrict__ kbuf, int krs,
    const short* __restrict__ vbuf, int vrs,
    short* __restrict__ obuf, int ors,
    const int* __restrict__ mask, int Tq, int Tk, float scale) {
  __shared__ short Ks[64][72];
  __shared__ short Vt[64][72];
  __shared__ short Ps[4][16][72];
  int qt = blockIdx.x, bh = blockIdx.y;
  int b = bh >> 4, h = bh & 15;
  int t = threadIdx.x, wid = t >> 6, lane = t & 63;
  int la = lane & 15, lb = lane >> 4;

  const short* qB = qbuf + (size_t)b * Tq * qrs + h * 64;
  const short* kB = kbuf + (size_t)b * Tk * krs + h * 64;
  const short* vB = vbuf + (size_t)b * Tk * vrs + h * 64;

  int q0 = qt * 64 + wid * 16;  // global q row base for this wave
  s8v qf[2];
#pragma unroll
  for (int kk = 0; kk < 2; kk++)
    qf[kk] = *(const s8v*)(qB + (size_t)(q0 + la) * qrs + kk * 32 + lb * 8);

  f32x4 accO[4];
#pragma unroll
  for (int n = 0; n < 4; n++) accO[n] = (f32x4){0.f, 0.f, 0.f, 0.f};
  float mj[4], lj[4];
#pragma unroll
  for (int j = 0; j < 4; j++) { mj[j] = -1e30f; lj[j] = 0.f; }

  int nkt = CAUSAL ? (qt + 1) : ((Tk + 63) >> 6);
  for (int kt = 0; kt < nkt; kt++) {
    int kb0 = kt * 64;
    // stage K (row-major, +8 pad) and V^T
#pragma unroll
    for (int i = 0; i < 2; i++) {
      int fl = i * 256 + t, r = fl >> 3, c = (fl & 7) << 3;
      int tk = kb0 + r; if (tk > Tk - 1) tk = Tk - 1;
      *(s8v*)&Ks[r][c] = *(const s8v*)(kB + (size_t)tk * krs + c);
      s8v vv = *(const s8v*)(vB + (size_t)tk * vrs + c);
#pragma unroll
      for (int j = 0; j < 8; j++) Vt[c + j][r] = vv[j];
    }
    __syncthreads();

    // S = Q @ K^T
    f32x4 sacc[4];
#pragma unroll
    for (int n = 0; n < 4; n++) {
      f32x4 a = (f32x4){0.f, 0.f, 0.f, 0.f};
#pragma unroll
      for (int kk = 0; kk < 2; kk++) {
        s8v kf = *(const s8v*)&Ks[n * 16 + la][kk * 32 + lb * 8];
        a = __builtin_amdgcn_mfma_f32_16x16x32_bf16(qf[kk], kf, a, 0, 0, 0);
      }
      sacc[n] = a;
    }
    // scale + mask + row max
    float tmax[4] = {-1e30f, -1e30f, -1e30f, -1e30f};
#pragma unroll
    for (int n = 0; n < 4; n++) {
      int kg = kb0 + n * 16 + la;
      bool okk = kg < Tk;
      if (mask) okk = okk && (mask[b * Tk + kg] != 0);
#pragma unroll
      for (int j = 0; j < 4; j++) {
        float s = sacc[n][j] * scale;
        bool ok = okk;
        if (CAUSAL) ok = ok && (kg <= q0 + lb * 4 + j);
        s = ok ? s : -1e30f;
        sacc[n][j] = s;
        tmax[j] = fmaxf(tmax[j], s);
      }
    }
#pragma unroll
    for (int d = 1; d < 16; d <<= 1)
#pragma unroll
      for (int j = 0; j < 4; j++) tmax[j] = fmaxf(tmax[j], __shfl_xor(tmax[j], d));
    float alpha[4], tsum[4] = {0.f, 0.f, 0.f, 0.f};
#pragma unroll
    for (int j = 0; j < 4; j++) {
      float mn_ = fmaxf(mj[j], tmax[j]);
      alpha[j] = __expf(mj[j] - mn_);
      mj[j] = mn_;
    }
    // P = exp(S-m), store transposed-ready in LDS (per-wave region)
#pragma unroll
    for (int n = 0; n < 4; n++)
#pragma unroll
      for (int j = 0; j < 4; j++) {
        float p = __expf(sacc[n][j] - mj[j]);
        tsum[j] += p;
        Ps[wid][lb * 4 + j][n * 16 + la] = f2bf(p);
      }
#pragma unroll
    for (int d = 1; d < 16; d <<= 1)
#pragma unroll
      for (int j = 0; j < 4; j++) tsum[j] += __shfl_xor(tsum[j], d);
#pragma unroll
    for (int j = 0; j < 4; j++) lj[j] = lj[j] * alpha[j] + tsum[j];
#pragma unroll
    for (int n = 0; n < 4; n++)
#pragma unroll
      for (int j = 0; j < 4; j++) accO[n][j] *= alpha[j];
    // O += P @ V
#pragma unroll
    for (int kk = 0; kk < 2; kk++) {
      s8v pf = *(const s8v*)&Ps[wid][la][kk * 32 + lb * 8];
#pragma unroll
      for (int n = 0; n < 4; n++) {
        s8v vf = *(const s8v*)&Vt[n * 16 + la][kk * 32 + lb * 8];
        accO[n] = __builtin_amdgcn_mfma_f32_16x16x32_bf16(pf, vf, accO[n], 0, 0, 0);
      }
    }
    __syncthreads();
  }
#pragma unroll
  for (int j = 0; j < 4; j++) {
    int r = q0 + lb * 4 + j;
    float inv = 1.f / lj[j];
#pragma unroll
    for (int n = 0; n < 4; n++)
      obuf[(size_t)(b * Tq + r) * ors + h * 64 + n * 16 + la] = f2bf(accO[n][j] * inv);
  }
}

// k,v slices of qkv (bf16) -> fp32 outputs, layout (B,T,H,DH) == [4096][1024]
__global__ __launch_bounds__(256) void k_copy_kv(
    const short* __restrict__ qkvb, float* __restrict__ ok, float* __restrict__ ov) {
  size_t i = (size_t)blockIdx.x * 256 + threadIdx.x;  // 4096*1024
  size_t row = i >> 10, col = i & 1023;
  ok[i] = bf2f(qkvb[row * 3072 + 1024 + col]);
  ov[i] = bf2f(qkvb[row * 3072 + 2048 + col]);
}

// ---------------------------------------------------------------------------
extern "C" void kernel_launch(void* const* d_in, const int* in_sizes, int n_in,
                              void* d_out, int out_size, void* d_ws, size_t ws_size,
                              hipStream_t stream) {
  (void)in_sizes; (void)n_in; (void)out_size;
  const float* x      = (const float*)d_in[0];
  const float* enc    = (const float*)d_in[1];
  const int*   mask   = (const int*)d_in[2];
  const float* w_qkv  = (const float*)d_in[3];
  const float* w_o_sa = (const float*)d_in[4];
  const float* w_q    = (const float*)d_in[5];
  const float* w_kv   = (const float*)d_in[6];
  const float* w_o_xa = (const float*)d_in[7];
  const float* w_ff1  = (const float*)d_in[8];
  const float* w_ff2  = (const float*)d_in[9];
  const float* g_sa   = (const float*)d_in[10];
  const float* g_xaq  = (const float*)d_in[11];
  const float* g_xam  = (const float*)d_in[12];
  const float* g_ff   = (const float*)d_in[13];

  float* out_x = (float*)d_out;
  float* out_k = out_x + (size_t)4096 * 1024;
  float* out_v = out_k + (size_t)4096 * 1024;

  char* ws = (char*)d_ws;
  size_t off = 0;
  auto alloc = [&](size_t bytes) -> void* {
    void* p = ws + off;
    off += (bytes + 255) & ~(size_t)255;
    return p;
  };
  short* wqkv_t = (short*)alloc((size_t)3072 * 1024 * 2);
  short* wosa_t = (short*)alloc((size_t)1024 * 1024 * 2);
  short* wq_t   = (short*)alloc((size_t)1024 * 1024 * 2);
  short* wkv_t  = (short*)alloc((size_t)2048 * 1024 * 2);
  short* woxa_t = (short*)alloc((size_t)1024 * 1024 * 2);
  short* wff1_t = (short*)alloc((size_t)4096 * 1024 * 2);
  short* wff2_t = (short*)alloc((size_t)1024 * 4096 * 2);
  short* xn     = (short*)alloc((size_t)4096 * 1024 * 2);
  short* qkv_b  = (short*)alloc((size_t)4096 * 3072 * 2);
  short* sa_b   = (short*)alloc((size_t)4096 * 1024 * 2);
  float* x1     = (float*)alloc((size_t)4096 * 1024 * 4);
  short* qn     = (short*)alloc((size_t)4096 * 1024 * 2);
  short* mn     = (short*)alloc((size_t)6000 * 1024 * 2);
  short* qx_b   = (short*)alloc((size_t)4096 * 1024 * 2);
  short* kvx_b  = (short*)alloc((size_t)6000 * 2048 * 2);
  short* xa_b   = (short*)alloc((size_t)4096 * 1024 * 2);
  float* x2     = (float*)alloc((size_t)4096 * 1024 * 4);
  short* hn     = (short*)alloc((size_t)4096 * 1024 * 2);
  short* h1     = (short*)alloc((size_t)4096 * 4096 * 2);
  (void)ws_size;

  // weights -> bf16 transposed
  k_transpose_cvt<<<dim3(96, 32), 256, 0, stream>>>(w_qkv, wqkv_t, 1024, 3072);
  k_transpose_cvt<<<dim3(32, 32), 256, 0, stream>>>(w_o_sa, wosa_t, 1024, 1024);
  k_transpose_cvt<<<dim3(32, 32), 256, 0, stream>>>(w_q, wq_t, 1024, 1024);
  k_transpose_cvt<<<dim3(64, 32), 256, 0, stream>>>(w_kv, wkv_t, 1024, 2048);
  k_transpose_cvt<<<dim3(32, 32), 256, 0, stream>>>(w_o_xa, woxa_t, 1024, 1024);
  k_transpose_cvt<<<dim3(128, 32), 256, 0, stream>>>(w_ff1, wff1_t, 1024, 4096);
  k_transpose_cvt<<<dim3(32, 128), 256, 0, stream>>>(w_ff2, wff2_t, 4096, 1024);

  // --- self-attention block ---
  k_ln<<<4096, 256, 0, stream>>>(x, g_sa, xn);
  k_gemm<false, false, false, true><<<dim3(32, 24), 256, 0, stream>>>(
      xn, wqkv_t, nullptr, qkv_b, nullptr, 4096, 3072, 1024);
  k_copy_kv<<<16384, 256, 0, stream>>>(qkv_b, out_k, out_v);
  k_attn<true><<<dim3(16, 64), 256, 0, stream>>>(
      qkv_b, 3072, qkv_b + 1024, 3072, qkv_b + 2048, 3072,
      sa_b, 1024, nullptr, 1024, 1024, 0.125f);
  k_gemm<true, false, true, false><<<dim3(32, 8), 256, 0, stream>>>(
      sa_b, wosa_t, x1, nullptr, x, 4096, 1024, 1024);

  // --- cross-attention block ---
  k_ln<<<4096, 256, 0, stream>>>(x1, g_xaq, qn);
  k_ln<<<6000, 256, 0, stream>>>(enc, g_xam, mn);
  k_gemm<false, false, false, true><<<dim3(32, 8), 256, 0, stream>>>(
      qn, wq_t, nullptr, qx_b, nullptr, 4096, 1024, 1024);
  k_gemm<false, false, false, true><<<dim3(47, 16), 256, 0, stream>>>(
      mn, wkv_t, nullptr, kvx_b, nullptr, 6000, 2048, 1024);
  k_attn<false><<<dim3(16, 64), 256, 0, stream>>>(
      qx_b, 1024, kvx_b, 2048, kvx_b + 1024, 2048,
      xa_b, 1024, mask, 1024, 1500, 0.125f);
  k_gemm<true, false, true, false><<<dim3(32, 8), 256, 0, stream>>>(
      xa_b, woxa_t, x2, nullptr, x1, 4096, 1024, 1024);

  // --- FFN block ---
  k_ln<<<4096, 256, 0, stream>>>(x2, g_ff, hn);
  k_gemm<false, true, false, true><<<dim3(32, 32), 256, 0, stream>>>(
      hn, wff1_t, nullptr, h1, nullptr, 4096, 4096, 1024);
  k_gemm<true, false, true, false><<<dim3(32, 8), 256, 0, stream>>>(
      h1, wff2_t, out_x, nullptr, x2, 4096, 1024, 4096);
}

// Round 2
// 593.054 us; speedup vs baseline: 1.0753x; 1.0753x over previous
//
#include <hip/hip_runtime.h>
#include <hip/hip_bf16.h>
#include <cstdint>
#include <cstddef>

// ---------------------------------------------------------------------------
// PrefillDecoderLayer on MI355X (gfx950).
// fp32 residual stream; GEMMs via bf16 MFMA 16x16x32 (m97-style 128x128 tile);
// flash attention v2: swapped QK^T (k lane-local), in-register softmax + P
// redistribution via ds_bpermute, pre-transposed V, XOR-swizzled LDS tiles.
// ---------------------------------------------------------------------------

typedef __attribute__((ext_vector_type(4))) float f32x4;
typedef __attribute__((ext_vector_type(8))) short s8v;   // 8 bf16 as raw bits

#define DEVI __device__ __forceinline__

DEVI short f2bf(float f) {  // RNE float -> bf16 bits
  union { float f; unsigned u; } x; x.f = f;
  unsigned r = x.u + 0x7fffu + ((x.u >> 16) & 1u);
  return (short)(r >> 16);
}
DEVI float bf2f(short s) {
  union { unsigned u; float f; } x; x.u = ((unsigned)(unsigned short)s) << 16;
  return x.f;
}
DEVI unsigned pack_bf2(float lo, float hi) {
  return ((unsigned)(unsigned short)f2bf(hi) << 16) | (unsigned)(unsigned short)f2bf(lo);
}
DEVI unsigned bperm(int srclane, unsigned v) {
  return (unsigned)__builtin_amdgcn_ds_bpermute(srclane << 2, (int)v);
}
DEVI float bpermf(int srclane, float v) {
  union { float f; int i; } x; x.f = v;
  x.i = __builtin_amdgcn_ds_bpermute(srclane << 2, x.i);
  return x.f;
}
DEVI void gload_lds16(const void* g, void* l) {
  __builtin_amdgcn_global_load_lds((const __attribute__((address_space(1))) void*)g,
                                   (__attribute__((address_space(3))) void*)l,
                                   16, 0, 0);
}

// ---------------------------------------------------------------------------
// Weight transpose + fp32->bf16:  w[K][N] f32  ->  wt[N][K] bf16
// ---------------------------------------------------------------------------
__global__ __launch_bounds__(256) void k_transpose_cvt(
    const float* __restrict__ w, short* __restrict__ wt, int K, int N) {
  __shared__ float tile[32][33];
  int n0 = blockIdx.x * 32, k0 = blockIdx.y * 32;
  int tx = threadIdx.x & 31, ty = threadIdx.x >> 5;
#pragma unroll
  for (int i = 0; i < 32; i += 8)
    tile[ty + i][tx] = w[(size_t)(k0 + ty + i) * N + n0 + tx];
  __syncthreads();
#pragma unroll
  for (int i = 0; i < 32; i += 8)
    wt[(size_t)(n0 + ty + i) * K + k0 + tx] = f2bf(tile[tx][ty + i]);
}

// ---------------------------------------------------------------------------
// Per-head V transpose: src[b*T+t][coff+h*64+d] -> dst[(b*16+h)][64][Tp]
// grid (Tp/32, B*H), 256 threads.
// ---------------------------------------------------------------------------
__global__ __launch_bounds__(256) void k_vtrans(
    const short* __restrict__ src, int srs, int coff,
    short* __restrict__ dst, int T, int Tp) {
  __shared__ short tile[32][72];
  int bh = blockIdx.y, b = bh >> 4, h = bh & 15;
  int t0 = blockIdx.x * 32;
  const short* sB = src + (size_t)b * T * srs + coff + h * 64;
  short* dB = dst + (size_t)bh * 64 * Tp;
  int t = threadIdx.x;
  int r = t >> 3, c = (t & 7) * 8;
  int tr = t0 + r; if (tr > T - 1) tr = T - 1;
  *(s8v*)&tile[r][c] = *(const s8v*)(sB + (size_t)tr * srs + c);
  __syncthreads();
  int d = t & 63, ch = t >> 6;  // ch 0..3 -> t-cols ch*8..+8
  s8v o;
#pragma unroll
  for (int j = 0; j < 8; j++) o[j] = tile[ch * 8 + j][d];
  *(s8v*)(dB + (size_t)d * Tp + t0 + ch * 8) = o;
}

// encoder mask -> 64-bit words (bit k = valid)
__global__ void k_maskpack(const int* __restrict__ mask,
                           unsigned long long* __restrict__ out, int Tk, int mw) {
  int b = blockIdx.x, w = threadIdx.x;
  if (w >= mw) return;
  unsigned long long v = 0;
  const int* mb = mask + (size_t)b * Tk;
#pragma unroll 4
  for (int j = 0; j < 64; j++) {
    int k = w * 64 + j;
    if (k < Tk && mb[k]) v |= (1ull << j);
  }
  out[(size_t)b * mw + w] = v;
}

// ---------------------------------------------------------------------------
// LayerNorm over D=1024, fp32 in -> bf16 out. One block (256 thr) per row.
// ---------------------------------------------------------------------------
__global__ __launch_bounds__(256) void k_ln(
    const float* __restrict__ x, const float* __restrict__ g,
    short* __restrict__ out) {
  int row = blockIdx.x;
  const float* xr = x + (size_t)row * 1024;
  int t = threadIdx.x, wid = t >> 6, lane = t & 63;
  float v[4]; float s = 0.f;
#pragma unroll
  for (int i = 0; i < 4; i++) { v[i] = xr[t + i * 256]; s += v[i]; }
#pragma unroll
  for (int m = 32; m >= 1; m >>= 1) s += __shfl_xor(s, m);
  __shared__ float red[4];
  if (lane == 0) red[wid] = s;
  __syncthreads();
  float mean = (red[0] + red[1] + red[2] + red[3]) * (1.f / 1024.f);
  float q = 0.f;
#pragma unroll
  for (int i = 0; i < 4; i++) { v[i] -= mean; q += v[i] * v[i]; }
#pragma unroll
  for (int m = 32; m >= 1; m >>= 1) q += __shfl_xor(q, m);
  __syncthreads();
  if (lane == 0) red[wid] = q;
  __syncthreads();
  float var = (red[0] + red[1] + red[2] + red[3]) * (1.f / 1024.f);
  float rs = rsqrtf(var + 1e-5f);
  short* orow = out + (size_t)row * 1024;
#pragma unroll
  for (int i = 0; i < 4; i++) orow[t + i * 256] = f2bf(v[i] * rs * g[t + i * 256]);
}

// ---------------------------------------------------------------------------
// GEMM: C[M][N] = A[M][K](bf16) @ Bt[N][K](bf16)^T  (+res, gelu, f32/bf16 out)
// ---------------------------------------------------------------------------
template <bool RES, bool GELU_, bool F32OUT, bool BF16OUT>
__global__ __launch_bounds__(256) void k_gemm(
    const short* __restrict__ A, const short* __restrict__ Bt,
    float* __restrict__ Cf, short* __restrict__ Cb,
    const float* __restrict__ res, int M, int N, int K) {
  __shared__ short As[128 * 32];
  __shared__ short Bs[128 * 32];
  int t = threadIdx.x, wid = t >> 6, lane = t & 63;
  int la = lane & 15, lb = lane >> 4;
  int wr = wid >> 1, wc = wid & 1;
  int am = blockIdx.x * 128, bn = blockIdx.y * 128;

  f32x4 acc[4][4];
#pragma unroll
  for (int m = 0; m < 4; m++)
#pragma unroll
    for (int n = 0; n < 4; n++) acc[m][n] = (f32x4){0.f, 0.f, 0.f, 0.f};

  for (int k0 = 0; k0 < K; k0 += 32) {
#pragma unroll
    for (int i = 0; i < 2; i++) {
      int fl = i * 256 + t;
      int r = fl >> 2, c = (fl & 3) << 3;
      int ar = am + r; if (ar > M - 1) ar = M - 1;
      gload_lds16(A + (size_t)ar * K + k0 + c, As + (size_t)(i * 256 + wid * 64) * 8);
      int br = bn + r;
      gload_lds16(Bt + (size_t)br * K + k0 + c, Bs + (size_t)(i * 256 + wid * 64) * 8);
    }
    __syncthreads();
    s8v af[4], bfg[4];
#pragma unroll
    for (int m = 0; m < 4; m++)
      af[m] = *(const s8v*)(As + (wr * 64 + m * 16 + la) * 32 + lb * 8);
#pragma unroll
    for (int n = 0; n < 4; n++)
      bfg[n] = *(const s8v*)(Bs + (wc * 64 + n * 16 + la) * 32 + lb * 8);
#pragma unroll
    for (int m = 0; m < 4; m++)
#pragma unroll
      for (int n = 0; n < 4; n++)
        acc[m][n] = __builtin_amdgcn_mfma_f32_16x16x32_bf16(af[m], bfg[n], acc[m][n], 0, 0, 0);
    __syncthreads();
  }

#pragma unroll
  for (int m = 0; m < 4; m++) {
    int rb = am + wr * 64 + m * 16 + lb * 4;
#pragma unroll
    for (int n = 0; n < 4; n++) {
      int col = bn + wc * 64 + n * 16 + la;
#pragma unroll
      for (int j = 0; j < 4; j++) {
        int r = rb + j;
        if (r < M) {
          float v = acc[m][n][j];
          if (RES) v += res[(size_t)r * N + col];
          if (GELU_) {
            float u = v;
            v = 0.5f * u * (1.f + tanhf(0.7978845608028654f * (u + 0.044715f * u * u * u)));
          }
          if (F32OUT) Cf[(size_t)r * N + col] = v;
          if (BF16OUT) Cb[(size_t)r * N + col] = f2bf(v);
        }
      }
    }
  }
}

// ---------------------------------------------------------------------------
// Flash attention v2. Grid (Tq/64, B*H), 256 thr (4 waves x 16 q-rows).
// Swapped QK^T: lane holds S[q=la][k=16n+lb*4+j]. V pre-transposed per head.
// K/V LDS tiles XOR-swizzled; P->A-frag via ds_bpermute (no P LDS).
// ---------------------------------------------------------------------------
template <bool CAUSAL>
__global__ __launch_bounds__(256) void k_attn2(
    const short* __restrict__ qbuf, int qrs,
    const short* __restrict__ kbuf, int krs,
    const short* __restrict__ vT, int vts,
    short* __restrict__ obuf, int ors,
    const unsigned long long* __restrict__ mbits, int mwords,
    int Tq, int Tk, float scale) {
  __shared__ short Ks[64 * 64];
  __shared__ short Vs[64 * 64];
  int qt = blockIdx.x, bh = blockIdx.y;
  int b = bh >> 4, h = bh & 15;
  int t = threadIdx.x, wid = t >> 6, lane = t & 63;
  int la = lane & 15, lb = lane >> 4;

  const short* qB = qbuf + (size_t)b * Tq * qrs + h * 64;
  const short* kB = kbuf + (size_t)b * Tk * krs + h * 64;
  const short* vB = vT + (size_t)bh * 64 * vts;

  int q0 = qt * 64 + wid * 16;
  s8v qf[2];
#pragma unroll
  for (int kk = 0; kk < 2; kk++)
    qf[kk] = *(const s8v*)(qB + (size_t)(q0 + la) * qrs + kk * 32 + lb * 8);

  f32x4 accO[4];
#pragma unroll
  for (int n = 0; n < 4; n++) accO[n] = (f32x4){0.f, 0.f, 0.f, 0.f};
  float m = -1e30f, l = 0.f;

  int nkt = CAUSAL ? (qt + 1) : ((Tk + 63) >> 6);

  // staging geometry: per pass 32 rows x 64 shorts; this thread: row sr(+32)
  int sr = t >> 3, scol = (t & 7) * 8;
  int swz = sr * 64 + (scol ^ ((sr & 7) << 3));  // same swizzle for sr+32
  s8v krg0, krg1, vrg0, vrg1;
  {
    int tk0 = sr; if (tk0 > Tk - 1) tk0 = Tk - 1;
    int tk1 = 32 + sr; if (tk1 > Tk - 1) tk1 = Tk - 1;
    krg0 = *(const s8v*)(kB + (size_t)tk0 * krs + scol);
    krg1 = *(const s8v*)(kB + (size_t)tk1 * krs + scol);
    vrg0 = *(const s8v*)(vB + (size_t)sr * vts + scol);
    vrg1 = *(const s8v*)(vB + (size_t)(32 + sr) * vts + scol);
  }

  for (int kt = 0; kt < nkt; kt++) {
    int kb0 = kt * 64;
    __syncthreads();
    *(s8v*)&Ks[swz] = krg0;
    *(s8v*)&Ks[swz + 32 * 64] = krg1;
    *(s8v*)&Vs[swz] = vrg0;
    *(s8v*)&Vs[swz + 32 * 64] = vrg1;
    __syncthreads();
    if (kt + 1 < nkt) {
      int kb = kb0 + 64;
      int tk0 = kb + sr; if (tk0 > Tk - 1) tk0 = Tk - 1;
      int tk1 = kb + 32 + sr; if (tk1 > Tk - 1) tk1 = Tk - 1;
      krg0 = *(const s8v*)(kB + (size_t)tk0 * krs + scol);
      krg1 = *(const s8v*)(kB + (size_t)tk1 * krs + scol);
      vrg0 = *(const s8v*)(vB + (size_t)sr * vts + kb + scol);
      vrg1 = *(const s8v*)(vB + (size_t)(32 + sr) * vts + kb + scol);
    }

    unsigned long long wm = CAUSAL ? ~0ull : mbits[(size_t)b * mwords + kt];

    // S^T = K @ Q^T : lane holds S[q=la][k=16n+lb*4+j]
    float sc[4][4];
    unsigned ok16 = 0;
#pragma unroll
    for (int n = 0; n < 4; n++) {
      f32x4 a = (f32x4){0.f, 0.f, 0.f, 0.f};
#pragma unroll
      for (int kk = 0; kk < 2; kk++) {
        s8v kf = *(const s8v*)&Ks[(n * 16 + la) * 64 + ((kk * 32 + lb * 8) ^ ((la & 7) << 3))];
        a = __builtin_amdgcn_mfma_f32_16x16x32_bf16(kf, qf[kk], a, 0, 0, 0);
      }
#pragma unroll
      for (int j = 0; j < 4; j++) {
        int ki = n * 16 + lb * 4 + j;
        bool ok = ((wm >> ki) & 1ull) != 0;
        if (CAUSAL) ok = ok && (kb0 + ki <= q0 + la);
        ok16 |= (unsigned)ok << (n * 4 + j);
        sc[n][j] = ok ? a[j] * scale : -1e30f;
      }
    }
    float tm = sc[0][0];
#pragma unroll
    for (int n = 0; n < 4; n++)
#pragma unroll
      for (int j = 0; j < 4; j++) tm = fmaxf(tm, sc[n][j]);
    tm = fmaxf(tm, __shfl_xor(tm, 16));
    tm = fmaxf(tm, __shfl_xor(tm, 32));
    float mn = fmaxf(m, tm);
    float alpha = __expf(m - mn);
    m = mn;

    unsigned W[4][2];
    float ps = 0.f;
#pragma unroll
    for (int n = 0; n < 4; n++) {
      float p[4];
#pragma unroll
      for (int j = 0; j < 4; j++) {
        float e = __expf(sc[n][j] - mn);
        p[j] = ((ok16 >> (n * 4 + j)) & 1) ? e : 0.f;
        ps += p[j];
      }
      W[n][0] = pack_bf2(p[0], p[1]);
      W[n][1] = pack_bf2(p[2], p[3]);
    }
    ps += __shfl_xor(ps, 16);
    ps += __shfl_xor(ps, 32);
    l = l * alpha + ps;

    // rescale O rows (O rows are q=lb*4+j; alpha lives at lane la=q)
#pragma unroll
    for (int j = 0; j < 4; j++) {
      float aj = bpermf(lb * 20 + j, alpha);
#pragma unroll
      for (int n = 0; n < 4; n++) accO[n][j] *= aj;
    }

    // build P A-frag (rows q=la, contig k) via bpermute and do PV
    int s0 = la + ((lb & 1) << 5);
    bool hi = (lb >> 1) != 0;
#pragma unroll
    for (int kk = 0; kk < 2; kk++) {
      unsigned w[4];
      {
        unsigned a0 = bperm(s0, W[2 * kk][0]), b0 = bperm(s0, W[2 * kk + 1][0]);
        unsigned a1 = bperm(s0, W[2 * kk][1]), b1 = bperm(s0, W[2 * kk + 1][1]);
        unsigned a2 = bperm(s0 + 16, W[2 * kk][0]), b2 = bperm(s0 + 16, W[2 * kk + 1][0]);
        unsigned a3 = bperm(s0 + 16, W[2 * kk][1]), b3 = bperm(s0 + 16, W[2 * kk + 1][1]);
        w[0] = hi ? b0 : a0;
        w[1] = hi ? b1 : a1;
        w[2] = hi ? b2 : a2;
        w[3] = hi ? b3 : a3;
      }
      s8v pa;
      __builtin_memcpy(&pa, w, 16);
#pragma unroll
      for (int n = 0; n < 4; n++) {
        s8v vf = *(const s8v*)&Vs[(n * 16 + la) * 64 + ((kk * 32 + lb * 8) ^ ((la & 7) << 3))];
        accO[n] = __builtin_amdgcn_mfma_f32_16x16x32_bf16(pa, vf, accO[n], 0, 0, 0);
      }
    }
  }

#pragma unroll
  for (int j = 0; j < 4; j++) {
    float lj = bpermf(lb * 20 + j, l);
    float inv = 1.f / lj;
    int r = q0 + lb * 4 + j;
#pragma unroll
    for (int n = 0; n < 4; n++)
      obuf[(size_t)(b * Tq + r) * ors + h * 64 + n * 16 + la] = f2bf(accO[n][j] * inv);
  }
}

// k,v slices of qkv (bf16) -> fp32 outputs, vectorized
__global__ __launch_bounds__(256) void k_copy_kv(
    const short* __restrict__ qkvb, float* __restrict__ ok, float* __restrict__ ov) {
  size_t i = (size_t)blockIdx.x * 256 + threadIdx.x;  // 524288 = 4096*1024/8
  size_t row = i >> 7, c8 = (i & 127) << 3;
  const short* base = qkvb + row * 3072;
  s8v kv = *(const s8v*)(base + 1024 + c8);
  s8v vv = *(const s8v*)(base + 2048 + c8);
  f32x4 k0, k1, v0, v1;
#pragma unroll
  for (int j = 0; j < 4; j++) {
    k0[j] = bf2f(kv[j]); k1[j] = bf2f(kv[4 + j]);
    v0[j] = bf2f(vv[j]); v1[j] = bf2f(vv[4 + j]);
  }
  float* okp = ok + row * 1024 + c8;
  float* ovp = ov + row * 1024 + c8;
  *(f32x4*)okp = k0; *(f32x4*)(okp + 4) = k1;
  *(f32x4*)ovp = v0; *(f32x4*)(ovp + 4) = v1;
}

// ---------------------------------------------------------------------------
extern "C" void kernel_launch(void* const* d_in, const int* in_sizes, int n_in,
                              void* d_out, int out_size, void* d_ws, size_t ws_size,
                              hipStream_t stream) {
  (void)in_sizes; (void)n_in; (void)out_size; (void)ws_size;
  const float* x      = (const float*)d_in[0];
  const float* enc    = (const float*)d_in[1];
  const int*   mask   = (const int*)d_in[2];
  const float* w_qkv  = (const float*)d_in[3];
  const float* w_o_sa = (const float*)d_in[4];
  const float* w_q    = (const float*)d_in[5];
  const float* w_kv   = (const float*)d_in[6];
  const float* w_o_xa = (const float*)d_in[7];
  const float* w_ff1  = (const float*)d_in[8];
  const float* w_ff2  = (const float*)d_in[9];
  const float* g_sa   = (const float*)d_in[10];
  const float* g_xaq  = (const float*)d_in[11];
  const float* g_xam  = (const float*)d_in[12];
  const float* g_ff   = (const float*)d_in[13];

  float* out_x = (float*)d_out;
  float* out_k = out_x + (size_t)4096 * 1024;
  float* out_v = out_k + (size_t)4096 * 1024;

  char* ws = (char*)d_ws;
  size_t off = 0;
  auto alloc = [&](size_t bytes) -> void* {
    void* p = ws + off;
    off += (bytes + 255) & ~(size_t)255;
    return p;
  };
  short* wqkv_t = (short*)alloc((size_t)3072 * 1024 * 2);
  short* wosa_t = (short*)alloc((size_t)1024 * 1024 * 2);
  short* wq_t   = (short*)alloc((size_t)1024 * 1024 * 2);
  short* wkv_t  = (short*)alloc((size_t)2048 * 1024 * 2);
  short* woxa_t = (short*)alloc((size_t)1024 * 1024 * 2);
  short* wff1_t = (short*)alloc((size_t)4096 * 1024 * 2);
  short* wff2_t = (short*)alloc((size_t)1024 * 4096 * 2);
  short* xn     = (short*)alloc((size_t)4096 * 1024 * 2);  // reused as vTsa
  short* qkv_b  = (short*)alloc((size_t)4096 * 3072 * 2);
  short* sa_b   = (short*)alloc((size_t)4096 * 1024 * 2);
  float* x1     = (float*)alloc((size_t)4096 * 1024 * 4);
  short* qn     = (short*)alloc((size_t)4096 * 1024 * 2);
  short* mn     = (short*)alloc((size_t)6000 * 1024 * 2);
  short* qx_b   = (short*)alloc((size_t)4096 * 1024 * 2);
  short* kvx_b  = (short*)alloc((size_t)6000 * 2048 * 2);
  short* xa_b   = (short*)alloc((size_t)4096 * 1024 * 2);
  float* x2     = (float*)alloc((size_t)4096 * 1024 * 4);
  short* hn     = (short*)alloc((size_t)4096 * 1024 * 2);
  short* h1     = (short*)alloc((size_t)4096 * 4096 * 2);  // first 12.6MB reused as vTxa
  unsigned long long* mbits = (unsigned long long*)alloc(4 * 24 * 8);

  short* vTsa = xn;            // [64 bh][64][1024]  (xn dead after qkv GEMM)
  short* vTxa = h1;            // [64 bh][64][1536]  (h1 written after XA attn)

  // weights -> bf16 transposed
  k_transpose_cvt<<<dim3(96, 32), 256, 0, stream>>>(w_qkv, wqkv_t, 1024, 3072);
  k_transpose_cvt<<<dim3(32, 32), 256, 0, stream>>>(w_o_sa, wosa_t, 1024, 1024);
  k_transpose_cvt<<<dim3(32, 32), 256, 0, stream>>>(w_q, wq_t, 1024, 1024);
  k_transpose_cvt<<<dim3(64, 32), 256, 0, stream>>>(w_kv, wkv_t, 1024, 2048);
  k_transpose_cvt<<<dim3(32, 32), 256, 0, stream>>>(w_o_xa, woxa_t, 1024, 1024);
  k_transpose_cvt<<<dim3(128, 32), 256, 0, stream>>>(w_ff1, wff1_t, 1024, 4096);
  k_transpose_cvt<<<dim3(32, 128), 256, 0, stream>>>(w_ff2, wff2_t, 4096, 1024);
  k_maskpack<<<4, 64, 0, stream>>>(mask, mbits, 1500, 24);

  // --- self-attention block ---
  k_ln<<<4096, 256, 0, stream>>>(x, g_sa, xn);
  k_gemm<false, false, false, true><<<dim3(32, 24), 256, 0, stream>>>(
      xn, wqkv_t, nullptr, qkv_b, nullptr, 4096, 3072, 1024);
  k_copy_kv<<<2048, 256, 0, stream>>>(qkv_b, out_k, out_v);
  k_vtrans<<<dim3(32, 64), 256, 0, stream>>>(qkv_b, 3072, 2048, vTsa, 1024, 1024);
  k_attn2<true><<<dim3(16, 64), 256, 0, stream>>>(
      qkv_b, 3072, qkv_b + 1024, 3072, vTsa, 1024,
      sa_b, 1024, nullptr, 0, 1024, 1024, 0.125f);
  k_gemm<true, false, true, false><<<dim3(32, 8), 256, 0, stream>>>(
      sa_b, wosa_t, x1, nullptr, x, 4096, 1024, 1024);

  // --- cross-attention block ---
  k_ln<<<4096, 256, 0, stream>>>(x1, g_xaq, qn);
  k_ln<<<6000, 256, 0, stream>>>(enc, g_xam, mn);
  k_gemm<false, false, false, true><<<dim3(32, 8), 256, 0, stream>>>(
      qn, wq_t, nullptr, qx_b, nullptr, 4096, 1024, 1024);
  k_gemm<false, false, false, true><<<dim3(47, 16), 256, 0, stream>>>(
      mn, wkv_t, nullptr, kvx_b, nullptr, 6000, 2048, 1024);
  k_vtrans<<<dim3(48, 64), 256, 0, stream>>>(kvx_b, 2048, 1024, vTxa, 1500, 1536);
  k_attn2<false><<<dim3(16, 64), 256, 0, stream>>>(
      qx_b, 1024, kvx_b, 2048, vTxa, 1536,
      xa_b, 1024, mbits, 24, 1024, 1500, 0.125f);
  k_gemm<true, false, true, false><<<dim3(32, 8), 256, 0, stream>>>(
      xa_b, woxa_t, x2, nullptr, x1, 4096, 1024, 1024);

  // --- FFN block ---
  k_ln<<<4096, 256, 0, stream>>>(x2, g_ff, hn);
  k_gemm<false, true, false, true><<<dim3(32, 32), 256, 0, stream>>>(
      hn, wff1_t, nullptr, h1, nullptr, 4096, 4096, 1024);
  k_gemm<true, false, true, false><<<dim3(32, 8), 256, 0, stream>>>(
      h1, wff2_t, out_x, nullptr, x2, 4096, 1024, 4096);
}

// Round 3
// 567.218 us; speedup vs baseline: 1.1243x; 1.0456x over previous
//
#include <hip/hip_runtime.h>
#include <hip/hip_bf16.h>
#include <cstdint>
#include <cstddef>

// ---------------------------------------------------------------------------
// PrefillDecoderLayer on MI355X (gfx950).
// fp32 residual stream; GEMMs via bf16 MFMA 16x16x32 (128x128 tile, split-K
// for low-parallelism shapes); flash attention v3: swapped QK^T, log2-domain
// softmax with defer-max, cvt_pk packing, mask fast-paths.
// ---------------------------------------------------------------------------

typedef __attribute__((ext_vector_type(4))) float f32x4;
typedef __attribute__((ext_vector_type(8))) short s8v;   // 8 bf16 as raw bits
typedef __attribute__((ext_vector_type(2))) unsigned uint2v;

#define DEVI __device__ __forceinline__

DEVI short f2bf(float f) {  // RNE float -> bf16 bits
  union { float f; unsigned u; } x; x.f = f;
  unsigned r = x.u + 0x7fffu + ((x.u >> 16) & 1u);
  return (short)(r >> 16);
}
DEVI float bf2f(short s) {
  union { unsigned u; float f; } x; x.u = ((unsigned)(unsigned short)s) << 16;
  return x.f;
}
DEVI unsigned cvtpk_bf2(float lo, float hi) {  // v_cvt_pk_bf16_f32 (RNE)
  unsigned r;
  asm("v_cvt_pk_bf16_f32 %0, %1, %2" : "=v"(r) : "v"(lo), "v"(hi));
  return r;
}
DEVI float fexp2(float x) {
  float r;
  asm("v_exp_f32 %0, %1" : "=v"(r) : "v"(x));
  return r;
}
DEVI unsigned bperm(int srclane, unsigned v) {
  return (unsigned)__builtin_amdgcn_ds_bpermute(srclane << 2, (int)v);
}
DEVI float bpermf(int srclane, float v) {
  union { float f; int i; } x; x.f = v;
  x.i = __builtin_amdgcn_ds_bpermute(srclane << 2, x.i);
  return x.f;
}
DEVI void gload_lds16(const void* g, void* l) {
  __builtin_amdgcn_global_load_lds((const __attribute__((address_space(1))) void*)g,
                                   (__attribute__((address_space(3))) void*)l,
                                   16, 0, 0);
}

// ---------------------------------------------------------------------------
// Weight transpose + fp32->bf16:  w[K][N] f32  ->  wt[N][K] bf16
// ---------------------------------------------------------------------------
__global__ __launch_bounds__(256) void k_transpose_cvt(
    const float* __restrict__ w, short* __restrict__ wt, int K, int N) {
  __shared__ float tile[32][33];
  int n0 = blockIdx.x * 32, k0 = blockIdx.y * 32;
  int tx = threadIdx.x & 31, ty = threadIdx.x >> 5;
#pragma unroll
  for (int i = 0; i < 32; i += 8)
    tile[ty + i][tx] = w[(size_t)(k0 + ty + i) * N + n0 + tx];
  __syncthreads();
#pragma unroll
  for (int i = 0; i < 32; i += 8)
    wt[(size_t)(n0 + ty + i) * K + k0 + tx] = f2bf(tile[tx][ty + i]);
}

// ---------------------------------------------------------------------------
// Per-head V transpose: src[b*T+t][coff+h*64+d] -> dst[(b*16+h)][64][Tp]
// ---------------------------------------------------------------------------
__global__ __launch_bounds__(256) void k_vtrans(
    const short* __restrict__ src, int srs, int coff,
    short* __restrict__ dst, int T, int Tp) {
  __shared__ short tile[32][72];
  int bh = blockIdx.y, b = bh >> 4, h = bh & 15;
  int t0 = blockIdx.x * 32;
  const short* sB = src + (size_t)b * T * srs + coff + h * 64;
  short* dB = dst + (size_t)bh * 64 * Tp;
  int t = threadIdx.x;
  int r = t >> 3, c = (t & 7) * 8;
  int tr = t0 + r; if (tr > T - 1) tr = T - 1;
  *(s8v*)&tile[r][c] = *(const s8v*)(sB + (size_t)tr * srs + c);
  __syncthreads();
  int d = t & 63, ch = t >> 6;
  s8v o;
#pragma unroll
  for (int j = 0; j < 8; j++) o[j] = tile[ch * 8 + j][d];
  *(s8v*)(dB + (size_t)d * Tp + t0 + ch * 8) = o;
}

// encoder mask -> 64-bit words (bit k = valid)
__global__ void k_maskpack(const int* __restrict__ mask,
                           unsigned long long* __restrict__ out, int Tk, int mw) {
  int b = blockIdx.x, w = threadIdx.x;
  if (w >= mw) return;
  unsigned long long v = 0;
  const int* mb = mask + (size_t)b * Tk;
#pragma unroll 4
  for (int j = 0; j < 64; j++) {
    int k = w * 64 + j;
    if (k < Tk && mb[k]) v |= (1ull << j);
  }
  out[(size_t)b * mw + w] = v;
}

// ---------------------------------------------------------------------------
// LayerNorm over D=1024, fp32 in -> bf16 out. One block (256 thr) per row.
// ---------------------------------------------------------------------------
__global__ __launch_bounds__(256) void k_ln(
    const float* __restrict__ x, const float* __restrict__ g,
    short* __restrict__ out) {
  int row = blockIdx.x;
  const float* xr = x + (size_t)row * 1024;
  int t = threadIdx.x, wid = t >> 6, lane = t & 63;
  f32x4 v = ((const f32x4*)xr)[t];
  float s = v[0] + v[1] + v[2] + v[3];
#pragma unroll
  for (int m = 32; m >= 1; m >>= 1) s += __shfl_xor(s, m);
  __shared__ float red[4];
  if (lane == 0) red[wid] = s;
  __syncthreads();
  float mean = (red[0] + red[1] + red[2] + red[3]) * (1.f / 1024.f);
  float q = 0.f;
#pragma unroll
  for (int i = 0; i < 4; i++) { v[i] -= mean; q += v[i] * v[i]; }
#pragma unroll
  for (int m = 32; m >= 1; m >>= 1) q += __shfl_xor(q, m);
  __syncthreads();
  if (lane == 0) red[wid] = q;
  __syncthreads();
  float var = (red[0] + red[1] + red[2] + red[3]) * (1.f / 1024.f);
  float rs = rsqrtf(var + 1e-5f);
  f32x4 gv = ((const f32x4*)g)[t];
  unsigned w0 = cvtpk_bf2(v[0] * rs * gv[0], v[1] * rs * gv[1]);
  unsigned w1 = cvtpk_bf2(v[2] * rs * gv[2], v[3] * rs * gv[3]);
  uint2v w = {w0, w1};
  *(uint2v*)(out + (size_t)row * 1024 + t * 4) = w;
}

// ---------------------------------------------------------------------------
// GEMM: C[M][N] = A[M][K](bf16) @ Bt[N][K](bf16)^T  (+res, gelu, f32/bf16 out)
// lda/ldb = row strides; blockIdx.z = split-K slice (K = per-slice extent,
// fp32 output goes to slab z*M*N).
// ---------------------------------------------------------------------------
template <bool RES, bool GELU_, bool F32OUT, bool BF16OUT>
__global__ __launch_bounds__(256) void k_gemm(
    const short* __restrict__ A, const short* __restrict__ Bt,
    float* __restrict__ Cf, short* __restrict__ Cb,
    const float* __restrict__ res, int M, int N, int K, int lda, int ldb) {
  __shared__ short As[128 * 32];
  __shared__ short Bs[128 * 32];
  int z = blockIdx.z;
  A += (size_t)z * K;
  Bt += (size_t)z * K;
  if (F32OUT) Cf += (size_t)z * M * N;
  int t = threadIdx.x, wid = t >> 6, lane = t & 63;
  int la = lane & 15, lb = lane >> 4;
  int wr = wid >> 1, wc = wid & 1;
  int am = blockIdx.x * 128, bn = blockIdx.y * 128;

  f32x4 acc[4][4];
#pragma unroll
  for (int m = 0; m < 4; m++)
#pragma unroll
    for (int n = 0; n < 4; n++) acc[m][n] = (f32x4){0.f, 0.f, 0.f, 0.f};

  for (int k0 = 0; k0 < K; k0 += 32) {
#pragma unroll
    for (int i = 0; i < 2; i++) {
      int fl = i * 256 + t;
      int r = fl >> 2, c = (fl & 3) << 3;
      int ar = am + r; if (ar > M - 1) ar = M - 1;
      gload_lds16(A + (size_t)ar * lda + k0 + c, As + (size_t)(i * 256 + wid * 64) * 8);
      int br = bn + r;
      gload_lds16(Bt + (size_t)br * ldb + k0 + c, Bs + (size_t)(i * 256 + wid * 64) * 8);
    }
    __syncthreads();
    s8v af[4], bfg[4];
#pragma unroll
    for (int m = 0; m < 4; m++)
      af[m] = *(const s8v*)(As + (wr * 64 + m * 16 + la) * 32 + lb * 8);
#pragma unroll
    for (int n = 0; n < 4; n++)
      bfg[n] = *(const s8v*)(Bs + (wc * 64 + n * 16 + la) * 32 + lb * 8);
#pragma unroll
    for (int m = 0; m < 4; m++)
#pragma unroll
      for (int n = 0; n < 4; n++)
        acc[m][n] = __builtin_amdgcn_mfma_f32_16x16x32_bf16(af[m], bfg[n], acc[m][n], 0, 0, 0);
    __syncthreads();
  }

#pragma unroll
  for (int m = 0; m < 4; m++) {
    int rb = am + wr * 64 + m * 16 + lb * 4;
#pragma unroll
    for (int n = 0; n < 4; n++) {
      int col = bn + wc * 64 + n * 16 + la;
#pragma unroll
      for (int j = 0; j < 4; j++) {
        int r = rb + j;
        if (r < M) {
          float v = acc[m][n][j];
          if (RES) v += res[(size_t)r * N + col];
          if (GELU_) {
            float u = v;
            float y = 0.7978845608f * u * (1.f + 0.044715f * u * u);
            float e = fexp2(fminf(y * 2.88539008f, 80.f));  // e^{2y}
            float th = (e - 1.f) * __builtin_amdgcn_rcpf(e + 1.f);
            v = 0.5f * u * (1.f + th);
          }
          if (F32OUT) Cf[(size_t)r * N + col] = v;
          if (BF16OUT) Cb[(size_t)r * N + col] = f2bf(v);
        }
      }
    }
  }
}

// out = res + p0+p1+p2+p3 (split-K reduce), f32x4 vectorized
__global__ __launch_bounds__(256) void k_red4(
    const f32x4* __restrict__ p, const f32x4* __restrict__ res,
    f32x4* __restrict__ out, int n) {
  size_t i = (size_t)blockIdx.x * 256 + threadIdx.x;
  f32x4 v = res[i] + (p[i] + p[i + (size_t)n]) +
            (p[i + 2 * (size_t)n] + p[i + 3 * (size_t)n]);
  out[i] = v;
}

// ---------------------------------------------------------------------------
// Flash attention v3. Grid (Tq/64, B*H), 256 thr (4 waves x 16 q-rows).
// Swapped QK^T: lane holds S[q=la][k=16n+lb*4+j]. V pre-transposed per head.
// log2-domain softmax; mask fast-paths; defer-max; cvt_pk packing.
// ---------------------------------------------------------------------------
template <bool CAUSAL>
__global__ __launch_bounds__(256) void k_attn2(
    const short* __restrict__ qbuf, int qrs,
    const short* __restrict__ kbuf, int krs,
    const short* __restrict__ vT, int vts,
    short* __restrict__ obuf, int ors,
    const unsigned long long* __restrict__ mbits, int mwords,
    int Tq, int Tk, float scale) {
  __shared__ short Ks[64 * 64];
  __shared__ short Vs[64 * 64];
  int qt = blockIdx.x, bh = blockIdx.y;
  int b = bh >> 4, h = bh & 15;
  int t = threadIdx.x, wid = t >> 6, lane = t & 63;
  int la = lane & 15, lb = lane >> 4;
  float lscale = scale * 1.44269504f;  // into log2 domain

  const short* qB = qbuf + (size_t)b * Tq * qrs + h * 64;
  const short* kB = kbuf + (size_t)b * Tk * krs + h * 64;
  const short* vB = vT + (size_t)bh * 64 * vts;

  int q0 = qt * 64 + wid * 16;
  s8v qf[2];
#pragma unroll
  for (int kk = 0; kk < 2; kk++)
    qf[kk] = *(const s8v*)(qB + (size_t)(q0 + la) * qrs + kk * 32 + lb * 8);

  f32x4 accO[4];
#pragma unroll
  for (int n = 0; n < 4; n++) accO[n] = (f32x4){0.f, 0.f, 0.f, 0.f};
  float m = -1e30f, l = 0.f;

  int nkt = CAUSAL ? (qt + 1) : ((Tk + 63) >> 6);

  int sr = t >> 3, scol = (t & 7) * 8;
  int swz = sr * 64 + (scol ^ ((sr & 7) << 3));
  s8v krg0, krg1, vrg0, vrg1;
  {
    int tk0 = sr; if (tk0 > Tk - 1) tk0 = Tk - 1;
    int tk1 = 32 + sr; if (tk1 > Tk - 1) tk1 = Tk - 1;
    krg0 = *(const s8v*)(kB + (size_t)tk0 * krs + scol);
    krg1 = *(const s8v*)(kB + (size_t)tk1 * krs + scol);
    vrg0 = *(const s8v*)(vB + (size_t)sr * vts + scol);
    vrg1 = *(const s8v*)(vB + (size_t)(32 + sr) * vts + scol);
  }

  for (int kt = 0; kt < nkt; kt++) {
    int kb0 = kt * 64;
    __syncthreads();
    *(s8v*)&Ks[swz] = krg0;
    *(s8v*)&Ks[swz + 32 * 64] = krg1;
    *(s8v*)&Vs[swz] = vrg0;
    *(s8v*)&Vs[swz + 32 * 64] = vrg1;
    __syncthreads();
    if (kt + 1 < nkt) {
      int kb = kb0 + 64;
      int tk0 = kb + sr; if (tk0 > Tk - 1) tk0 = Tk - 1;
      int tk1 = kb + 32 + sr; if (tk1 > Tk - 1) tk1 = Tk - 1;
      krg0 = *(const s8v*)(kB + (size_t)tk0 * krs + scol);
      krg1 = *(const s8v*)(kB + (size_t)tk1 * krs + scol);
      vrg0 = *(const s8v*)(vB + (size_t)sr * vts + kb + scol);
      vrg1 = *(const s8v*)(vB + (size_t)(32 + sr) * vts + kb + scol);
    }

    bool needMask;
    unsigned long long wm = ~0ull;
    if (CAUSAL) {
      needMask = (kt == qt);  // only diagonal tiles need element checks
    } else {
      wm = mbits[(size_t)b * mwords + kt];
      needMask = (wm != ~0ull);
    }

    // S^T = K @ Q^T : lane holds S[q=la][k=16n+lb*4+j], log2 domain
    float sc[4][4];
    __builtin_amdgcn_s_setprio(1);
#pragma unroll
    for (int n = 0; n < 4; n++) {
      f32x4 a = (f32x4){0.f, 0.f, 0.f, 0.f};
#pragma unroll
      for (int kk = 0; kk < 2; kk++) {
        s8v kf = *(const s8v*)&Ks[(n * 16 + la) * 64 + ((kk * 32 + lb * 8) ^ ((la & 7) << 3))];
        a = __builtin_amdgcn_mfma_f32_16x16x32_bf16(kf, qf[kk], a, 0, 0, 0);
      }
#pragma unroll
      for (int j = 0; j < 4; j++) {
        float s = a[j] * lscale;
        if (needMask) {
          int ki = n * 16 + lb * 4 + j;
          bool ok = ((wm >> ki) & 1ull) != 0;
          if (CAUSAL) ok = (kb0 + ki <= q0 + la);
          s = ok ? s : -1e30f;
        }
        sc[n][j] = s;
      }
    }
    __builtin_amdgcn_s_setprio(0);

    float tm = sc[0][0];
#pragma unroll
    for (int n = 0; n < 4; n++)
#pragma unroll
      for (int j = 0; j < 4; j++) tm = fmaxf(tm, sc[n][j]);
    tm = fmaxf(tm, __shfl_xor(tm, 16));
    tm = fmaxf(tm, __shfl_xor(tm, 32));
    tm = fmaxf(tm, -1e4f);  // floor: masked rows decay to p=0 naturally

    bool skip = __all(tm - m <= 10.f);  // defer-max (T13), log2 units
    float alpha = 1.f;
    if (!skip) {
      float mn_ = fmaxf(m, tm);
      alpha = fexp2(m - mn_);
      m = mn_;
    }

    unsigned W[4][2];
    float ps = 0.f;
#pragma unroll
    for (int n = 0; n < 4; n++) {
      float p0 = fexp2(sc[n][0] - m), p1 = fexp2(sc[n][1] - m);
      float p2 = fexp2(sc[n][2] - m), p3 = fexp2(sc[n][3] - m);
      ps += (p0 + p1) + (p2 + p3);
      W[n][0] = cvtpk_bf2(p0, p1);
      W[n][1] = cvtpk_bf2(p2, p3);
    }
    ps += __shfl_xor(ps, 16);
    ps += __shfl_xor(ps, 32);
    l = l * alpha + ps;

    if (!skip) {
#pragma unroll
      for (int j = 0; j < 4; j++) {
        float aj = bpermf(lb * 20 + j, alpha);
#pragma unroll
        for (int n = 0; n < 4; n++) accO[n][j] *= aj;
      }
    }

    // build P A-frag (rows q=la, contig k) via bpermute and do PV
    int s0 = la + ((lb & 1) << 5);
    bool hi = (lb >> 1) != 0;
    __builtin_amdgcn_s_setprio(1);
#pragma unroll
    for (int kk = 0; kk < 2; kk++) {
      unsigned w[4];
      {
        unsigned a0 = bperm(s0, W[2 * kk][0]), b0 = bperm(s0, W[2 * kk + 1][0]);
        unsigned a1 = bperm(s0, W[2 * kk][1]), b1 = bperm(s0, W[2 * kk + 1][1]);
        unsigned a2 = bperm(s0 + 16, W[2 * kk][0]), b2 = bperm(s0 + 16, W[2 * kk + 1][0]);
        unsigned a3 = bperm(s0 + 16, W[2 * kk][1]), b3 = bperm(s0 + 16, W[2 * kk + 1][1]);
        w[0] = hi ? b0 : a0;
        w[1] = hi ? b1 : a1;
        w[2] = hi ? b2 : a2;
        w[3] = hi ? b3 : a3;
      }
      s8v pa;
      __builtin_memcpy(&pa, w, 16);
#pragma unroll
      for (int n = 0; n < 4; n++) {
        s8v vf = *(const s8v*)&Vs[(n * 16 + la) * 64 + ((kk * 32 + lb * 8) ^ ((la & 7) << 3))];
        accO[n] = __builtin_amdgcn_mfma_f32_16x16x32_bf16(pa, vf, accO[n], 0, 0, 0);
      }
    }
    __builtin_amdgcn_s_setprio(0);
  }

#pragma unroll
  for (int j = 0; j < 4; j++) {
    float lj = bpermf(lb * 20 + j, l);
    float inv = 1.f / lj;
    int r = q0 + lb * 4 + j;
#pragma unroll
    for (int n = 0; n < 4; n++)
      obuf[(size_t)(b * Tq + r) * ors + h * 64 + n * 16 + la] = f2bf(accO[n][j] * inv);
  }
}

// k,v slices of qkv (bf16) -> fp32 outputs, vectorized
__global__ __launch_bounds__(256) void k_copy_kv(
    const short* __restrict__ qkvb, float* __restrict__ ok, float* __restrict__ ov) {
  size_t i = (size_t)blockIdx.x * 256 + threadIdx.x;
  size_t row = i >> 7, c8 = (i & 127) << 3;
  const short* base = qkvb + row * 3072;
  s8v kv = *(const s8v*)(base + 1024 + c8);
  s8v vv = *(const s8v*)(base + 2048 + c8);
  f32x4 k0, k1, v0, v1;
#pragma unroll
  for (int j = 0; j < 4; j++) {
    k0[j] = bf2f(kv[j]); k1[j] = bf2f(kv[4 + j]);
    v0[j] = bf2f(vv[j]); v1[j] = bf2f(vv[4 + j]);
  }
  float* okp = ok + row * 1024 + c8;
  float* ovp = ov + row * 1024 + c8;
  *(f32x4*)okp = k0; *(f32x4*)(okp + 4) = k1;
  *(f32x4*)ovp = v0; *(f32x4*)(ovp + 4) = v1;
}

// ---------------------------------------------------------------------------
extern "C" void kernel_launch(void* const* d_in, const int* in_sizes, int n_in,
                              void* d_out, int out_size, void* d_ws, size_t ws_size,
                              hipStream_t stream) {
  (void)in_sizes; (void)n_in; (void)out_size; (void)ws_size;
  const float* x      = (const float*)d_in[0];
  const float* enc    = (const float*)d_in[1];
  const int*   mask   = (const int*)d_in[2];
  const float* w_qkv  = (const float*)d_in[3];
  const float* w_o_sa = (const float*)d_in[4];
  const float* w_q    = (const float*)d_in[5];
  const float* w_kv   = (const float*)d_in[6];
  const float* w_o_xa = (const float*)d_in[7];
  const float* w_ff1  = (const float*)d_in[8];
  const float* w_ff2  = (const float*)d_in[9];
  const float* g_sa   = (const float*)d_in[10];
  const float* g_xaq  = (const float*)d_in[11];
  const float* g_xam  = (const float*)d_in[12];
  const float* g_ff   = (const float*)d_in[13];

  float* out_x = (float*)d_out;
  float* out_k = out_x + (size_t)4096 * 1024;
  float* out_v = out_k + (size_t)4096 * 1024;

  char* ws = (char*)d_ws;
  size_t off = 0;
  auto alloc = [&](size_t bytes) -> void* {
    void* p = ws + off;
    off += (bytes + 255) & ~(size_t)255;
    return p;
  };
  short* wqkv_t = (short*)alloc((size_t)3072 * 1024 * 2);
  short* wosa_t = (short*)alloc((size_t)1024 * 1024 * 2);
  short* wq_t   = (short*)alloc((size_t)1024 * 1024 * 2);
  short* wkv_t  = (short*)alloc((size_t)2048 * 1024 * 2);
  short* woxa_t = (short*)alloc((size_t)1024 * 1024 * 2);
  short* wff1_t = (short*)alloc((size_t)4096 * 1024 * 2);
  short* wff2_t = (short*)alloc((size_t)1024 * 4096 * 2);
  short* xn     = (short*)alloc((size_t)4096 * 1024 * 2);  // reused as vTsa
  short* qkv_b  = (short*)alloc((size_t)4096 * 3072 * 2);  // + ff2 partial slab
  short* sa_b   = (short*)alloc((size_t)4096 * 1024 * 2);
  float* x1     = (float*)alloc((size_t)4096 * 1024 * 4);
  short* qn     = (short*)alloc((size_t)4096 * 1024 * 2);
  short* mn     = (short*)alloc((size_t)6000 * 1024 * 2);
  short* qx_b   = (short*)alloc((size_t)4096 * 1024 * 2);
  short* kvx_b  = (short*)alloc((size_t)6000 * 2048 * 2);
  short* xa_b   = (short*)alloc((size_t)4096 * 1024 * 2);
  float* x2     = (float*)alloc((size_t)4096 * 1024 * 4);
  short* hn     = (short*)alloc((size_t)4096 * 1024 * 2);
  short* h1     = (short*)alloc((size_t)4096 * 4096 * 2);  // first 12.6MB reused as vTxa
  unsigned long long* mbits = (unsigned long long*)alloc(4 * 24 * 8);

  short* vTsa = xn;            // [64 bh][64][1024]
  short* vTxa = h1;            // [64 bh][64][1536]
  float* part = (float*)qkv_b; // 64MB split-K partials (qkv_b..mn all dead by ff2)

  // weights -> bf16 transposed
  k_transpose_cvt<<<dim3(96, 32), 256, 0, stream>>>(w_qkv, wqkv_t, 1024, 3072);
  k_transpose_cvt<<<dim3(32, 32), 256, 0, stream>>>(w_o_sa, wosa_t, 1024, 1024);
  k_transpose_cvt<<<dim3(32, 32), 256, 0, stream>>>(w_q, wq_t, 1024, 1024);
  k_transpose_cvt<<<dim3(64, 32), 256, 0, stream>>>(w_kv, wkv_t, 1024, 2048);
  k_transpose_cvt<<<dim3(32, 32), 256, 0, stream>>>(w_o_xa, woxa_t, 1024, 1024);
  k_transpose_cvt<<<dim3(128, 32), 256, 0, stream>>>(w_ff1, wff1_t, 1024, 4096);
  k_transpose_cvt<<<dim3(32, 128), 256, 0, stream>>>(w_ff2, wff2_t, 4096, 1024);
  k_maskpack<<<4, 64, 0, stream>>>(mask, mbits, 1500, 24);

  // --- self-attention block ---
  k_ln<<<4096, 256, 0, stream>>>(x, g_sa, xn);
  k_gemm<false, false, false, true><<<dim3(32, 24), 256, 0, stream>>>(
      xn, wqkv_t, nullptr, qkv_b, nullptr, 4096, 3072, 1024, 1024, 1024);
  k_copy_kv<<<2048, 256, 0, stream>>>(qkv_b, out_k, out_v);
  k_vtrans<<<dim3(32, 64), 256, 0, stream>>>(qkv_b, 3072, 2048, vTsa, 1024, 1024);
  k_attn2<true><<<dim3(16, 64), 256, 0, stream>>>(
      qkv_b, 3072, qkv_b + 1024, 3072, vTsa, 1024,
      sa_b, 1024, nullptr, 0, 1024, 1024, 0.125f);
  k_gemm<true, false, true, false><<<dim3(32, 8), 256, 0, stream>>>(
      sa_b, wosa_t, x1, nullptr, x, 4096, 1024, 1024, 1024, 1024);

  // --- cross-attention block ---
  k_ln<<<4096, 256, 0, stream>>>(x1, g_xaq, qn);
  k_ln<<<6000, 256, 0, stream>>>(enc, g_xam, mn);
  k_gemm<false, false, false, true><<<dim3(32, 8), 256, 0, stream>>>(
      qn, wq_t, nullptr, qx_b, nullptr, 4096, 1024, 1024, 1024, 1024);
  k_gemm<false, false, false, true><<<dim3(47, 16), 256, 0, stream>>>(
      mn, wkv_t, nullptr, kvx_b, nullptr, 6000, 2048, 1024, 1024, 1024);
  k_vtrans<<<dim3(48, 64), 256, 0, stream>>>(kvx_b, 2048, 1024, vTxa, 1500, 1536);
  k_attn2<false><<<dim3(16, 64), 256, 0, stream>>>(
      qx_b, 1024, kvx_b, 2048, vTxa, 1536,
      xa_b, 1024, mbits, 24, 1024, 1500, 0.125f);
  k_gemm<true, false, true, false><<<dim3(32, 8), 256, 0, stream>>>(
      xa_b, woxa_t, x2, nullptr, x1, 4096, 1024, 1024, 1024, 1024);

  // --- FFN block ---
  k_ln<<<4096, 256, 0, stream>>>(x2, g_ff, hn);
  k_gemm<false, true, false, true><<<dim3(32, 32), 256, 0, stream>>>(
      hn, wff1_t, nullptr, h1, nullptr, 4096, 4096, 1024, 1024, 1024);
  // ff2: split-K x4 (K=1024 each), partials + reduce(+residual)
  k_gemm<false, false, true, false><<<dim3(32, 8, 4), 256, 0, stream>>>(
      h1, wff2_t, part, nullptr, nullptr, 4096, 1024, 1024, 4096, 4096);
  k_red4<<<4096, 256, 0, stream>>>(
      (const f32x4*)part, (const f32x4*)x2, (f32x4*)out_x, 1048576);
}

// Round 4
// 455.790 us; speedup vs baseline: 1.3991x; 1.2445x over previous
//
#include <hip/hip_runtime.h>
#include <hip/hip_bf16.h>
#include <cstdint>
#include <cstddef>

// ---------------------------------------------------------------------------
// PrefillDecoderLayer on MI355X (gfx950).
// fp32 residual stream; GEMMs via bf16 MFMA 16x16x32 (128x128 tile, BK=64,
// XOR-swizzled LDS, split-K for ff2); flash attention v4: 8-wave blocks,
// swapped QK^T, log2 softmax + defer-max, P via per-wave swizzled LDS scratch,
// paired causal supertiles.
// ---------------------------------------------------------------------------

typedef __attribute__((ext_vector_type(4))) float f32x4;
typedef __attribute__((ext_vector_type(8))) short s8v;   // 8 bf16 as raw bits
typedef __attribute__((ext_vector_type(2))) unsigned uint2v;

#define DEVI __device__ __forceinline__

DEVI short f2bf(float f) {  // RNE float -> bf16 bits
  union { float f; unsigned u; } x; x.f = f;
  unsigned r = x.u + 0x7fffu + ((x.u >> 16) & 1u);
  return (short)(r >> 16);
}
DEVI float bf2f(short s) {
  union { unsigned u; float f; } x; x.u = ((unsigned)(unsigned short)s) << 16;
  return x.f;
}
DEVI unsigned cvtpk_bf2(float lo, float hi) {  // v_cvt_pk_bf16_f32 (RNE)
  unsigned r;
  asm("v_cvt_pk_bf16_f32 %0, %1, %2" : "=v"(r) : "v"(lo), "v"(hi));
  return r;
}
DEVI float fexp2(float x) {
  float r;
  asm("v_exp_f32 %0, %1" : "=v"(r) : "v"(x));
  return r;
}
DEVI float bpermf(int srclane, float v) {
  union { float f; int i; } x; x.f = v;
  x.i = __builtin_amdgcn_ds_bpermute(srclane << 2, x.i);
  return x.f;
}
DEVI void gload_lds16(const void* g, void* l) {
  __builtin_amdgcn_global_load_lds((const __attribute__((address_space(1))) void*)g,
                                   (__attribute__((address_space(3))) void*)l,
                                   16, 0, 0);
}

// ---------------------------------------------------------------------------
// Weight transpose + fp32->bf16:  w[K][N] f32  ->  wt[N][K] bf16
// ---------------------------------------------------------------------------
__global__ __launch_bounds__(256) void k_transpose_cvt(
    const float* __restrict__ w, short* __restrict__ wt, int K, int N) {
  __shared__ float tile[32][33];
  int n0 = blockIdx.x * 32, k0 = blockIdx.y * 32;
  int tx = threadIdx.x & 31, ty = threadIdx.x >> 5;
#pragma unroll
  for (int i = 0; i < 32; i += 8)
    tile[ty + i][tx] = w[(size_t)(k0 + ty + i) * N + n0 + tx];
  __syncthreads();
#pragma unroll
  for (int i = 0; i < 32; i += 8)
    wt[(size_t)(n0 + ty + i) * K + k0 + tx] = f2bf(tile[tx][ty + i]);
}

// ---------------------------------------------------------------------------
// Per-head V transpose: src[b*T+t][coff+h*64+d] -> dst[(b*16+h)][64][Tp]
// ---------------------------------------------------------------------------
__global__ __launch_bounds__(256) void k_vtrans(
    const short* __restrict__ src, int srs, int coff,
    short* __restrict__ dst, int T, int Tp) {
  __shared__ short tile[32][72];
  int bh = blockIdx.y, b = bh >> 4, h = bh & 15;
  int t0 = blockIdx.x * 32;
  const short* sB = src + (size_t)b * T * srs + coff + h * 64;
  short* dB = dst + (size_t)bh * 64 * Tp;
  int t = threadIdx.x;
  int r = t >> 3, c = (t & 7) * 8;
  int tr = t0 + r; if (tr > T - 1) tr = T - 1;
  *(s8v*)&tile[r][c] = *(const s8v*)(sB + (size_t)tr * srs + c);
  __syncthreads();
  int d = t & 63, ch = t >> 6;
  s8v o;
#pragma unroll
  for (int j = 0; j < 8; j++) o[j] = tile[ch * 8 + j][d];
  *(s8v*)(dB + (size_t)d * Tp + t0 + ch * 8) = o;
}

// encoder mask -> 64-bit words (bit k = valid)
__global__ void k_maskpack(const int* __restrict__ mask,
                           unsigned long long* __restrict__ out, int Tk, int mw) {
  int b = blockIdx.x, w = threadIdx.x;
  if (w >= mw) return;
  unsigned long long v = 0;
  const int* mb = mask + (size_t)b * Tk;
#pragma unroll 4
  for (int j = 0; j < 64; j++) {
    int k = w * 64 + j;
    if (k < Tk && mb[k]) v |= (1ull << j);
  }
  out[(size_t)b * mw + w] = v;
}

// ---------------------------------------------------------------------------
// LayerNorm over D=1024, fp32 in -> bf16 out. One block (256 thr) per row.
// ---------------------------------------------------------------------------
__global__ __launch_bounds__(256) void k_ln(
    const float* __restrict__ x, const float* __restrict__ g,
    short* __restrict__ out) {
  int row = blockIdx.x;
  const float* xr = x + (size_t)row * 1024;
  int t = threadIdx.x, wid = t >> 6, lane = t & 63;
  f32x4 v = ((const f32x4*)xr)[t];
  float s = v[0] + v[1] + v[2] + v[3];
#pragma unroll
  for (int m = 32; m >= 1; m >>= 1) s += __shfl_xor(s, m);
  __shared__ float red[4];
  if (lane == 0) red[wid] = s;
  __syncthreads();
  float mean = (red[0] + red[1] + red[2] + red[3]) * (1.f / 1024.f);
  float q = 0.f;
#pragma unroll
  for (int i = 0; i < 4; i++) { v[i] -= mean; q += v[i] * v[i]; }
#pragma unroll
  for (int m = 32; m >= 1; m >>= 1) q += __shfl_xor(q, m);
  __syncthreads();
  if (lane == 0) red[wid] = q;
  __syncthreads();
  float var = (red[0] + red[1] + red[2] + red[3]) * (1.f / 1024.f);
  float rs = rsqrtf(var + 1e-5f);
  f32x4 gv = ((const f32x4*)g)[t];
  unsigned w0 = cvtpk_bf2(v[0] * rs * gv[0], v[1] * rs * gv[1]);
  unsigned w1 = cvtpk_bf2(v[2] * rs * gv[2], v[3] * rs * gv[3]);
  uint2v w = {w0, w1};
  *(uint2v*)(out + (size_t)row * 1024 + t * 4) = w;
}

// ---------------------------------------------------------------------------
// GEMM: C[M][N] = A[M][K](bf16) @ Bt[N][K](bf16)^T  (+res, gelu, f32/bf16 out)
// 128x128 tile, BK=64, XOR-swizzled LDS (byte ^= (row&7)<<4 via pre-swizzled
// global source). blockIdx.z = split-K slice.
// ---------------------------------------------------------------------------
template <bool RES, bool GELU_, bool F32OUT, bool BF16OUT>
__global__ __launch_bounds__(256) void k_gemm(
    const short* __restrict__ A, const short* __restrict__ Bt,
    float* __restrict__ Cf, short* __restrict__ Cb,
    const float* __restrict__ res, int M, int N, int K, int lda, int ldb) {
  __shared__ short As[128 * 64];
  __shared__ short Bs[128 * 64];
  int z = blockIdx.z;
  A += (size_t)z * K;
  Bt += (size_t)z * K;
  if (F32OUT) Cf += (size_t)z * M * N;
  int t = threadIdx.x, wid = t >> 6, lane = t & 63;
  int la = lane & 15, lb = lane >> 4;
  int wr = wid >> 1, wc = wid & 1;
  int am = blockIdx.x * 128, bn = blockIdx.y * 128;

  f32x4 acc[4][4];
#pragma unroll
  for (int m = 0; m < 4; m++)
#pragma unroll
    for (int n = 0; n < 4; n++) acc[m][n] = (f32x4){0.f, 0.f, 0.f, 0.f};

  for (int k0 = 0; k0 < K; k0 += 64) {
#pragma unroll
    for (int i = 0; i < 4; i++) {
      int fl = i * 256 + t;
      int r = fl >> 3;
      int c = ((fl & 7) ^ (r & 7)) << 3;  // pre-swizzled source col (shorts)
      int ar = am + r; if (ar > M - 1) ar = M - 1;
      gload_lds16(A + (size_t)ar * lda + k0 + c, As + (size_t)(i * 256 + wid * 64) * 8);
      int br = bn + r;
      gload_lds16(Bt + (size_t)br * ldb + k0 + c, Bs + (size_t)(i * 256 + wid * 64) * 8);
    }
    __syncthreads();
#pragma unroll
    for (int kk = 0; kk < 2; kk++) {
      s8v af[4], bfg[4];
#pragma unroll
      for (int m = 0; m < 4; m++)
        af[m] = *(const s8v*)(As + (wr * 64 + m * 16 + la) * 64 +
                              ((kk * 32 + lb * 8) ^ ((la & 7) << 3)));
#pragma unroll
      for (int n = 0; n < 4; n++)
        bfg[n] = *(const s8v*)(Bs + (wc * 64 + n * 16 + la) * 64 +
                               ((kk * 32 + lb * 8) ^ ((la & 7) << 3)));
#pragma unroll
      for (int m = 0; m < 4; m++)
#pragma unroll
        for (int n = 0; n < 4; n++)
          acc[m][n] = __builtin_amdgcn_mfma_f32_16x16x32_bf16(af[m], bfg[n], acc[m][n], 0, 0, 0);
    }
    __syncthreads();
  }

#pragma unroll
  for (int m = 0; m < 4; m++) {
    int rb = am + wr * 64 + m * 16 + lb * 4;
#pragma unroll
    for (int n = 0; n < 4; n++) {
      int col = bn + wc * 64 + n * 16 + la;
#pragma unroll
      for (int j = 0; j < 4; j++) {
        int r = rb + j;
        if (r < M) {
          float v = acc[m][n][j];
          if (RES) v += res[(size_t)r * N + col];
          if (GELU_) {
            float u = v;
            float y = 0.7978845608f * u * (1.f + 0.044715f * u * u);
            float e = fexp2(fminf(y * 2.88539008f, 80.f));  // e^{2y}
            float th = (e - 1.f) * __builtin_amdgcn_rcpf(e + 1.f);
            v = 0.5f * u * (1.f + th);
          }
          if (F32OUT) Cf[(size_t)r * N + col] = v;
          if (BF16OUT) Cb[(size_t)r * N + col] = f2bf(v);
        }
      }
    }
  }
}

// out = res + p0+p1+p2+p3 (split-K reduce), f32x4 vectorized
__global__ __launch_bounds__(256) void k_red4(
    const f32x4* __restrict__ p, const f32x4* __restrict__ res,
    f32x4* __restrict__ out, int n) {
  size_t i = (size_t)blockIdx.x * 256 + threadIdx.x;
  f32x4 v = res[i] + (p[i] + p[i + (size_t)n]) +
            (p[i + 2 * (size_t)n] + p[i + 3 * (size_t)n]);
  out[i] = v;
}

// ---------------------------------------------------------------------------
// Flash attention v4. 512 thr = 8 waves x 16 q-rows = 128 q/block.
// CAUSAL: grid (4,64), block handles supertiles {bx, 7-bx} (balanced 18 tiles);
// else grid (8,64). Swapped QK^T (lane holds S[q=la][k]); V pre-transposed.
// P redistributed through per-wave XOR-swizzled LDS scratch (no bpermute).
// ---------------------------------------------------------------------------
template <bool CAUSAL>
__global__ __launch_bounds__(512) void k_attn4(
    const short* __restrict__ qbuf, int qrs,
    const short* __restrict__ kbuf, int krs,
    const short* __restrict__ vT, int vts,
    short* __restrict__ obuf, int ors,
    const unsigned long long* __restrict__ mbits, int mwords,
    int Tq, int Tk, float scale) {
  __shared__ short Ks[64 * 64];
  __shared__ short Vs[64 * 64];
  __shared__ short Ps[8 * 1024];
  int bh = blockIdx.y, b = bh >> 4, h = bh & 15;
  int t = threadIdx.x, wid = t >> 6, lane = t & 63;
  int la = lane & 15, lb = lane >> 4;
  float lscale = scale * 1.44269504f;  // log2 domain

  const short* qB = qbuf + (size_t)b * Tq * qrs + h * 64;
  const short* kB = kbuf + (size_t)b * Tk * krs + h * 64;
  const short* vB = vT + (size_t)bh * 64 * vts;
  char* Pw = (char*)(Ps + wid * 1024);  // 16 rows x 128B per wave

  int sr = t >> 3, scol = (t & 7) * 8;
  int swz = sr * 64 + (scol ^ ((sr & 7) << 3));

  int nsup = CAUSAL ? 2 : 1;
  for (int s = 0; s < nsup; s++) {
    int st = CAUSAL ? (s ? 7 - blockIdx.x : blockIdx.x) : blockIdx.x;
    int q0 = st * 128 + wid * 16;
    int nkt = CAUSAL ? 2 * st + 2 : (Tk + 63) >> 6;
    int lastkt = CAUSAL ? (q0 >> 6) : nkt - 1;

    s8v qf[2];
#pragma unroll
    for (int kk = 0; kk < 2; kk++)
      qf[kk] = *(const s8v*)(qB + (size_t)(q0 + la) * qrs + kk * 32 + lb * 8);

    f32x4 accO[4];
#pragma unroll
    for (int n = 0; n < 4; n++) accO[n] = (f32x4){0.f, 0.f, 0.f, 0.f};
    float m = -1e30f, l = 0.f;

    s8v krg, vrg;
    {
      int tk = sr; if (tk > Tk - 1) tk = Tk - 1;
      krg = *(const s8v*)(kB + (size_t)tk * krs + scol);
      vrg = *(const s8v*)(vB + (size_t)sr * vts + scol);
    }

    for (int kt = 0; kt < nkt; kt++) {
      int kb0 = kt << 6;
      __syncthreads();
      *(s8v*)&Ks[swz] = krg;
      *(s8v*)&Vs[swz] = vrg;
      __syncthreads();
      if (kt + 1 < nkt) {
        int kb = kb0 + 64;
        int tk = kb + sr; if (tk > Tk - 1) tk = Tk - 1;
        krg = *(const s8v*)(kB + (size_t)tk * krs + scol);
        vrg = *(const s8v*)(vB + (size_t)sr * vts + kb + scol);
      }
      if (kt > lastkt) continue;  // fully-masked tile for this wave

      bool needMask;
      unsigned long long wm = ~0ull;
      if (CAUSAL) {
        needMask = (kt == lastkt);
      } else {
        wm = mbits[(size_t)b * mwords + kt];
        needMask = (wm != ~0ull);
      }

      // S^T = K @ Q^T : lane holds S[q=la][k=16n+lb*4+j], log2 domain
      float sc[4][4];
      __builtin_amdgcn_s_setprio(1);
#pragma unroll
      for (int n = 0; n < 4; n++) {
        f32x4 a = (f32x4){0.f, 0.f, 0.f, 0.f};
#pragma unroll
        for (int kk = 0; kk < 2; kk++) {
          s8v kf = *(const s8v*)&Ks[(n * 16 + la) * 64 +
                                    ((kk * 32 + lb * 8) ^ ((la & 7) << 3))];
          a = __builtin_amdgcn_mfma_f32_16x16x32_bf16(kf, qf[kk], a, 0, 0, 0);
        }
#pragma unroll
        for (int j = 0; j < 4; j++) {
          float sv = a[j] * lscale;
          if (needMask) {
            int ki = n * 16 + lb * 4 + j;
            bool ok = CAUSAL ? (kb0 + ki <= q0 + la) : (((wm >> ki) & 1ull) != 0);
            sv = ok ? sv : -1e30f;
          }
          sc[n][j] = sv;
        }
      }
      __builtin_amdgcn_s_setprio(0);

      float tm = sc[0][0];
#pragma unroll
      for (int n = 0; n < 4; n++)
#pragma unroll
        for (int j = 0; j < 4; j++) tm = fmaxf(tm, sc[n][j]);
      tm = fmaxf(tm, __shfl_xor(tm, 16));
      tm = fmaxf(tm, __shfl_xor(tm, 32));
      tm = fmaxf(tm, -1e4f);  // floor: masked rows decay to p=0 naturally

      bool skip = __all(tm - m <= 10.f);  // defer-max (T13)
      float alpha = 1.f;
      if (!skip) {
        float mn_ = fmaxf(m, tm);
        alpha = fexp2(m - mn_);
        m = mn_;
      }

      unsigned W[4][2];
      float ps = 0.f;
#pragma unroll
      for (int n = 0; n < 4; n++) {
        float p0 = fexp2(sc[n][0] - m), p1 = fexp2(sc[n][1] - m);
        float p2 = fexp2(sc[n][2] - m), p3 = fexp2(sc[n][3] - m);
        ps += (p0 + p1) + (p2 + p3);
        W[n][0] = cvtpk_bf2(p0, p1);
        W[n][1] = cvtpk_bf2(p2, p3);
      }
      ps += __shfl_xor(ps, 16);
      ps += __shfl_xor(ps, 32);
      l = l * alpha + ps;

      if (!skip) {
#pragma unroll
        for (int j = 0; j < 4; j++) {
          float aj = bpermf(lb * 20 + j, alpha);
#pragma unroll
          for (int n = 0; n < 4; n++) accO[n][j] *= aj;
        }
      }

      // P -> per-wave LDS scratch (swizzled), then PV
#pragma unroll
      for (int n = 0; n < 4; n++) {
        uint2v w2 = {W[n][0], W[n][1]};
        *(uint2v*)(Pw + ((la * 128 + n * 32 + lb * 8) ^ ((la & 7) << 4))) = w2;
      }
      __builtin_amdgcn_s_setprio(1);
#pragma unroll
      for (int kk = 0; kk < 2; kk++) {
        s8v pa = *(const s8v*)(Pw + ((la * 128 + kk * 64 + lb * 16) ^ ((la & 7) << 4)));
#pragma unroll
        for (int n = 0; n < 4; n++) {
          s8v vf = *(const s8v*)&Vs[(n * 16 + la) * 64 +
                                    ((kk * 32 + lb * 8) ^ ((la & 7) << 3))];
          accO[n] = __builtin_amdgcn_mfma_f32_16x16x32_bf16(pa, vf, accO[n], 0, 0, 0);
        }
      }
      __builtin_amdgcn_s_setprio(0);
    }

#pragma unroll
    for (int j = 0; j < 4; j++) {
      float lj = bpermf(lb * 20 + j, l);
      float inv = 1.f / lj;
      int r = q0 + lb * 4 + j;
#pragma unroll
      for (int n = 0; n < 4; n++)
        obuf[(size_t)(b * Tq + r) * ors + h * 64 + n * 16 + la] = f2bf(accO[n][j] * inv);
    }
  }
}

// k,v slices of qkv (bf16) -> fp32 outputs, vectorized
__global__ __launch_bounds__(256) void k_copy_kv(
    const short* __restrict__ qkvb, float* __restrict__ ok, float* __restrict__ ov) {
  size_t i = (size_t)blockIdx.x * 256 + threadIdx.x;
  size_t row = i >> 7, c8 = (i & 127) << 3;
  const short* base = qkvb + row * 3072;
  s8v kv = *(const s8v*)(base + 1024 + c8);
  s8v vv = *(const s8v*)(base + 2048 + c8);
  f32x4 k0, k1, v0, v1;
#pragma unroll
  for (int j = 0; j < 4; j++) {
    k0[j] = bf2f(kv[j]); k1[j] = bf2f(kv[4 + j]);
    v0[j] = bf2f(vv[j]); v1[j] = bf2f(vv[4 + j]);
  }
  float* okp = ok + row * 1024 + c8;
  float* ovp = ov + row * 1024 + c8;
  *(f32x4*)okp = k0; *(f32x4*)(okp + 4) = k1;
  *(f32x4*)ovp = v0; *(f32x4*)(ovp + 4) = v1;
}

// ---------------------------------------------------------------------------
extern "C" void kernel_launch(void* const* d_in, const int* in_sizes, int n_in,
                              void* d_out, int out_size, void* d_ws, size_t ws_size,
                              hipStream_t stream) {
  (void)in_sizes; (void)n_in; (void)out_size; (void)ws_size;
  const float* x      = (const float*)d_in[0];
  const float* enc    = (const float*)d_in[1];
  const int*   mask   = (const int*)d_in[2];
  const float* w_qkv  = (const float*)d_in[3];
  const float* w_o_sa = (const float*)d_in[4];
  const float* w_q    = (const float*)d_in[5];
  const float* w_kv   = (const float*)d_in[6];
  const float* w_o_xa = (const float*)d_in[7];
  const float* w_ff1  = (const float*)d_in[8];
  const float* w_ff2  = (const float*)d_in[9];
  const float* g_sa   = (const float*)d_in[10];
  const float* g_xaq  = (const float*)d_in[11];
  const float* g_xam  = (const float*)d_in[12];
  const float* g_ff   = (const float*)d_in[13];

  float* out_x = (float*)d_out;
  float* out_k = out_x + (size_t)4096 * 1024;
  float* out_v = out_k + (size_t)4096 * 1024;

  char* ws = (char*)d_ws;
  size_t off = 0;
  auto alloc = [&](size_t bytes) -> void* {
    void* p = ws + off;
    off += (bytes + 255) & ~(size_t)255;
    return p;
  };
  short* wqkv_t = (short*)alloc((size_t)3072 * 1024 * 2);
  short* wosa_t = (short*)alloc((size_t)1024 * 1024 * 2);
  short* wq_t   = (short*)alloc((size_t)1024 * 1024 * 2);
  short* wkv_t  = (short*)alloc((size_t)2048 * 1024 * 2);
  short* woxa_t = (short*)alloc((size_t)1024 * 1024 * 2);
  short* wff1_t = (short*)alloc((size_t)4096 * 1024 * 2);
  short* wff2_t = (short*)alloc((size_t)1024 * 4096 * 2);
  short* xn     = (short*)alloc((size_t)4096 * 1024 * 2);  // reused as vTsa
  short* qkv_b  = (short*)alloc((size_t)4096 * 3072 * 2);  // + ff2 partial slab
  short* sa_b   = (short*)alloc((size_t)4096 * 1024 * 2);
  float* x1     = (float*)alloc((size_t)4096 * 1024 * 4);
  short* qn     = (short*)alloc((size_t)4096 * 1024 * 2);
  short* mn     = (short*)alloc((size_t)6000 * 1024 * 2);
  short* qx_b   = (short*)alloc((size_t)4096 * 1024 * 2);
  short* kvx_b  = (short*)alloc((size_t)6000 * 2048 * 2);
  short* xa_b   = (short*)alloc((size_t)4096 * 1024 * 2);
  float* x2     = (float*)alloc((size_t)4096 * 1024 * 4);
  short* hn     = (short*)alloc((size_t)4096 * 1024 * 2);
  short* h1     = (short*)alloc((size_t)4096 * 4096 * 2);  // first 12.6MB reused as vTxa
  unsigned long long* mbits = (unsigned long long*)alloc(4 * 24 * 8);

  short* vTsa = xn;            // [64 bh][64][1024]
  short* vTxa = h1;            // [64 bh][64][1536]
  float* part = (float*)qkv_b; // 64MB split-K partials (dead by ff2 time)

  // weights -> bf16 transposed
  k_transpose_cvt<<<dim3(96, 32), 256, 0, stream>>>(w_qkv, wqkv_t, 1024, 3072);
  k_transpose_cvt<<<dim3(32, 32), 256, 0, stream>>>(w_o_sa, wosa_t, 1024, 1024);
  k_transpose_cvt<<<dim3(32, 32), 256, 0, stream>>>(w_q, wq_t, 1024, 1024);
  k_transpose_cvt<<<dim3(64, 32), 256, 0, stream>>>(w_kv, wkv_t, 1024, 2048);
  k_transpose_cvt<<<dim3(32, 32), 256, 0, stream>>>(w_o_xa, woxa_t, 1024, 1024);
  k_transpose_cvt<<<dim3(128, 32), 256, 0, stream>>>(w_ff1, wff1_t, 1024, 4096);
  k_transpose_cvt<<<dim3(32, 128), 256, 0, stream>>>(w_ff2, wff2_t, 4096, 1024);
  k_maskpack<<<4, 64, 0, stream>>>(mask, mbits, 1500, 24);

  // --- self-attention block ---
  k_ln<<<4096, 256, 0, stream>>>(x, g_sa, xn);
  k_gemm<false, false, false, true><<<dim3(32, 24), 256, 0, stream>>>(
      xn, wqkv_t, nullptr, qkv_b, nullptr, 4096, 3072, 1024, 1024, 1024);
  k_copy_kv<<<2048, 256, 0, stream>>>(qkv_b, out_k, out_v);
  k_vtrans<<<dim3(32, 64), 256, 0, stream>>>(qkv_b, 3072, 2048, vTsa, 1024, 1024);
  k_attn4<true><<<dim3(4, 64), 512, 0, stream>>>(
      qkv_b, 3072, qkv_b + 1024, 3072, vTsa, 1024,
      sa_b, 1024, nullptr, 0, 1024, 1024, 0.125f);
  k_gemm<true, false, true, false><<<dim3(32, 8), 256, 0, stream>>>(
      sa_b, wosa_t, x1, nullptr, x, 4096, 1024, 1024, 1024, 1024);

  // --- cross-attention block ---
  k_ln<<<4096, 256, 0, stream>>>(x1, g_xaq, qn);
  k_ln<<<6000, 256, 0, stream>>>(enc, g_xam, mn);
  k_gemm<false, false, false, true><<<dim3(32, 8), 256, 0, stream>>>(
      qn, wq_t, nullptr, qx_b, nullptr, 4096, 1024, 1024, 1024, 1024);
  k_gemm<false, false, false, true><<<dim3(47, 16), 256, 0, stream>>>(
      mn, wkv_t, nullptr, kvx_b, nullptr, 6000, 2048, 1024, 1024, 1024);
  k_vtrans<<<dim3(48, 64), 256, 0, stream>>>(kvx_b, 2048, 1024, vTxa, 1500, 1536);
  k_attn4<false><<<dim3(8, 64), 512, 0, stream>>>(
      qx_b, 1024, kvx_b, 2048, vTxa, 1536,
      xa_b, 1024, mbits, 24, 1024, 1500, 0.125f);
  k_gemm<true, false, true, false><<<dim3(32, 8), 256, 0, stream>>>(
      xa_b, woxa_t, x2, nullptr, x1, 4096, 1024, 1024, 1024, 1024);

  // --- FFN block ---
  k_ln<<<4096, 256, 0, stream>>>(x2, g_ff, hn);
  k_gemm<false, true, false, true><<<dim3(32, 32), 256, 0, stream>>>(
      hn, wff1_t, nullptr, h1, nullptr, 4096, 4096, 1024, 1024, 1024);
  // ff2: split-K x4 (K=1024 each), partials + reduce(+residual)
  k_gemm<false, false, true, false><<<dim3(32, 8, 4), 256, 0, stream>>>(
      h1, wff2_t, part, nullptr, nullptr, 4096, 1024, 1024, 4096, 4096);
  k_red4<<<4096, 256, 0, stream>>>(
      (const f32x4*)part, (const f32x4*)x2, (f32x4*)out_x, 1048576);
}

// Round 5
// 452.912 us; speedup vs baseline: 1.4080x; 1.0064x over previous
//
#include <hip/hip_runtime.h>
#include <hip/hip_bf16.h>
#include <cstdint>
#include <cstddef>

// ---------------------------------------------------------------------------
// PrefillDecoderLayer on MI355X (gfx950).
// fp32 residual stream; GEMMs via bf16 MFMA 16x16x32, 128x128 tile, BK=64,
// XOR-swizzled LDS, 2-phase double-buffered pipeline (T3-min), XCD swizzle,
// split-K x2 for ff2; flash attention v4 (8-wave, swapped QK^T, log2 softmax,
// defer-max, per-wave LDS P-redistribution, paired causal supertiles).
// ---------------------------------------------------------------------------

typedef __attribute__((ext_vector_type(4))) float f32x4;
typedef __attribute__((ext_vector_type(8))) short s8v;   // 8 bf16 as raw bits
typedef __attribute__((ext_vector_type(2))) unsigned uint2v;

#define DEVI __device__ __forceinline__

DEVI short f2bf(float f) {  // RNE float -> bf16 bits
  union { float f; unsigned u; } x; x.f = f;
  unsigned r = x.u + 0x7fffu + ((x.u >> 16) & 1u);
  return (short)(r >> 16);
}
DEVI float bf2f(short s) {
  union { unsigned u; float f; } x; x.u = ((unsigned)(unsigned short)s) << 16;
  return x.f;
}
DEVI unsigned cvtpk_bf2(float lo, float hi) {  // v_cvt_pk_bf16_f32 (RNE)
  unsigned r;
  asm("v_cvt_pk_bf16_f32 %0, %1, %2" : "=v"(r) : "v"(lo), "v"(hi));
  return r;
}
DEVI float fexp2(float x) {
  float r;
  asm("v_exp_f32 %0, %1" : "=v"(r) : "v"(x));
  return r;
}
DEVI float bpermf(int srclane, float v) {
  union { float f; int i; } x; x.f = v;
  x.i = __builtin_amdgcn_ds_bpermute(srclane << 2, x.i);
  return x.f;
}
DEVI void gload_lds16(const void* g, void* l) {
  __builtin_amdgcn_global_load_lds((const __attribute__((address_space(1))) void*)g,
                                   (__attribute__((address_space(3))) void*)l,
                                   16, 0, 0);
}

// ---------------------------------------------------------------------------
// Weight transpose + fp32->bf16:  w[K][N] f32  ->  wt[N][K] bf16
// ---------------------------------------------------------------------------
__global__ __launch_bounds__(256) void k_transpose_cvt(
    const float* __restrict__ w, short* __restrict__ wt, int K, int N) {
  __shared__ float tile[32][33];
  int n0 = blockIdx.x * 32, k0 = blockIdx.y * 32;
  int tx = threadIdx.x & 31, ty = threadIdx.x >> 5;
#pragma unroll
  for (int i = 0; i < 32; i += 8)
    tile[ty + i][tx] = w[(size_t)(k0 + ty + i) * N + n0 + tx];
  __syncthreads();
#pragma unroll
  for (int i = 0; i < 32; i += 8)
    wt[(size_t)(n0 + ty + i) * K + k0 + tx] = f2bf(tile[tx][ty + i]);
}

// ---------------------------------------------------------------------------
// Per-head V transpose: src[b*T+t][coff+h*64+d] -> dst[(b*16+h)][64][Tp]
// ---------------------------------------------------------------------------
__global__ __launch_bounds__(256) void k_vtrans(
    const short* __restrict__ src, int srs, int coff,
    short* __restrict__ dst, int T, int Tp) {
  __shared__ short tile[32][72];
  int bh = blockIdx.y, b = bh >> 4, h = bh & 15;
  int t0 = blockIdx.x * 32;
  const short* sB = src + (size_t)b * T * srs + coff + h * 64;
  short* dB = dst + (size_t)bh * 64 * Tp;
  int t = threadIdx.x;
  int r = t >> 3, c = (t & 7) * 8;
  int tr = t0 + r; if (tr > T - 1) tr = T - 1;
  *(s8v*)&tile[r][c] = *(const s8v*)(sB + (size_t)tr * srs + c);
  __syncthreads();
  int d = t & 63, ch = t >> 6;
  s8v o;
#pragma unroll
  for (int j = 0; j < 8; j++) o[j] = tile[ch * 8 + j][d];
  *(s8v*)(dB + (size_t)d * Tp + t0 + ch * 8) = o;
}

// encoder mask -> 64-bit words (bit k = valid)
__global__ void k_maskpack(const int* __restrict__ mask,
                           unsigned long long* __restrict__ out, int Tk, int mw) {
  int b = blockIdx.x, w = threadIdx.x;
  if (w >= mw) return;
  unsigned long long v = 0;
  const int* mb = mask + (size_t)b * Tk;
#pragma unroll 4
  for (int j = 0; j < 64; j++) {
    int k = w * 64 + j;
    if (k < Tk && mb[k]) v |= (1ull << j);
  }
  out[(size_t)b * mw + w] = v;
}

// ---------------------------------------------------------------------------
// LayerNorm over D=1024, fp32 in -> bf16 out. One block (256 thr) per row.
// ---------------------------------------------------------------------------
__global__ __launch_bounds__(256) void k_ln(
    const float* __restrict__ x, const float* __restrict__ g,
    short* __restrict__ out) {
  int row = blockIdx.x;
  const float* xr = x + (size_t)row * 1024;
  int t = threadIdx.x, wid = t >> 6, lane = t & 63;
  f32x4 v = ((const f32x4*)xr)[t];
  float s = v[0] + v[1] + v[2] + v[3];
#pragma unroll
  for (int m = 32; m >= 1; m >>= 1) s += __shfl_xor(s, m);
  __shared__ float red[4];
  if (lane == 0) red[wid] = s;
  __syncthreads();
  float mean = (red[0] + red[1] + red[2] + red[3]) * (1.f / 1024.f);
  float q = 0.f;
#pragma unroll
  for (int i = 0; i < 4; i++) { v[i] -= mean; q += v[i] * v[i]; }
#pragma unroll
  for (int m = 32; m >= 1; m >>= 1) q += __shfl_xor(q, m);
  __syncthreads();
  if (lane == 0) red[wid] = q;
  __syncthreads();
  float var = (red[0] + red[1] + red[2] + red[3]) * (1.f / 1024.f);
  float rs = rsqrtf(var + 1e-5f);
  f32x4 gv = ((const f32x4*)g)[t];
  unsigned w0 = cvtpk_bf2(v[0] * rs * gv[0], v[1] * rs * gv[1]);
  unsigned w1 = cvtpk_bf2(v[2] * rs * gv[2], v[3] * rs * gv[3]);
  uint2v w = {w0, w1};
  *(uint2v*)(out + (size_t)row * 1024 + t * 4) = w;
}

// ---------------------------------------------------------------------------
// GEMM: C[M][N] = A[M][K](bf16) @ Bt[N][K](bf16)^T  (+res, gelu, f32/bf16 out,
// fused fp32 k/v export). 128x128 tile, BK=64, XOR-swizzled LDS, 2-phase
// double-buffered pipeline, XCD-aware block swizzle. blockIdx.z = split-K.
// ---------------------------------------------------------------------------
template <bool RES, bool GELU_, bool F32OUT, bool BF16OUT, bool KV>
__global__ __launch_bounds__(256) void k_gemm(
    const short* __restrict__ A, const short* __restrict__ Bt,
    float* __restrict__ Cf, short* __restrict__ Cb,
    const float* __restrict__ res, float* __restrict__ okv,
    int M, int N, int K, int lda, int ldb) {
  __shared__ short As0[128 * 64];
  __shared__ short Bs0[128 * 64];
  __shared__ short As1[128 * 64];
  __shared__ short Bs1[128 * 64];
  int z = blockIdx.z;
  A += (size_t)z * K;
  Bt += (size_t)z * K;
  if (F32OUT) Cf += (size_t)z * M * N;

  // XCD-aware bijective swizzle of the xy grid (all grids are %8==0)
  int nxy = gridDim.x * gridDim.y;
  int orig = blockIdx.y * gridDim.x + blockIdx.x;
  int cpx = nxy >> 3;
  int swzb = (orig & 7) * cpx + (orig >> 3);
  int bx = swzb % gridDim.x, by = swzb / gridDim.x;

  int t = threadIdx.x, wid = t >> 6, lane = t & 63;
  int la = lane & 15, lb = lane >> 4;
  int wr = wid >> 1, wc = wid & 1;
  int am = bx * 128, bn = by * 128;

  f32x4 acc[4][4];
#pragma unroll
  for (int m = 0; m < 4; m++)
#pragma unroll
    for (int n = 0; n < 4; n++) acc[m][n] = (f32x4){0.f, 0.f, 0.f, 0.f};

  auto STAGE = [&](short* Asb, short* Bsb, int k0) {
#pragma unroll
    for (int i = 0; i < 4; i++) {
      int fl = i * 256 + t;
      int r = fl >> 3;
      int c = ((fl & 7) ^ (r & 7)) << 3;  // pre-swizzled source col (shorts)
      int ar = am + r; if (ar > M - 1) ar = M - 1;
      gload_lds16(A + (size_t)ar * lda + k0 + c, Asb + (size_t)(i * 256 + wid * 64) * 8);
      gload_lds16(Bt + (size_t)(bn + r) * ldb + k0 + c, Bsb + (size_t)(i * 256 + wid * 64) * 8);
    }
  };
  auto COMP = [&](const short* Asb, const short* Bsb) {
#pragma unroll
    for (int kk = 0; kk < 2; kk++) {
      s8v af[4], bfg[4];
#pragma unroll
      for (int m = 0; m < 4; m++)
        af[m] = *(const s8v*)(Asb + (wr * 64 + m * 16 + la) * 64 +
                              ((kk * 32 + lb * 8) ^ ((la & 7) << 3)));
#pragma unroll
      for (int n = 0; n < 4; n++)
        bfg[n] = *(const s8v*)(Bsb + (wc * 64 + n * 16 + la) * 64 +
                               ((kk * 32 + lb * 8) ^ ((la & 7) << 3)));
#pragma unroll
      for (int m = 0; m < 4; m++)
#pragma unroll
        for (int n = 0; n < 4; n++)
          acc[m][n] = __builtin_amdgcn_mfma_f32_16x16x32_bf16(af[m], bfg[n], acc[m][n], 0, 0, 0);
    }
  };

  STAGE(As0, Bs0, 0);
  __syncthreads();
  int nk = K >> 6;  // even for all shapes used here
  for (int kb = 0; kb < nk; kb += 2) {
    STAGE(As1, Bs1, (kb + 1) << 6);   // issue next-tile loads
    COMP(As0, Bs0);                   // compute current (loads land under MFMA)
    __syncthreads();
    if (kb + 2 < nk) STAGE(As0, Bs0, (kb + 2) << 6);
    COMP(As1, Bs1);
    __syncthreads();
  }

#pragma unroll
  for (int m = 0; m < 4; m++) {
    int rb = am + wr * 64 + m * 16 + lb * 4;
#pragma unroll
    for (int n = 0; n < 4; n++) {
      int col = bn + wc * 64 + n * 16 + la;
#pragma unroll
      for (int j = 0; j < 4; j++) {
        int r = rb + j;
        if (r < M) {
          float v = acc[m][n][j];
          if (RES) v += res[(size_t)r * N + col];
          if (GELU_) {
            float u = v;
            float y = 0.7978845608f * u * (1.f + 0.044715f * u * u);
            float e = fexp2(fminf(y * 2.88539008f, 80.f));  // e^{2y}
            float th = (e - 1.f) * __builtin_amdgcn_rcpf(e + 1.f);
            v = 0.5f * u * (1.f + th);
          }
          if (F32OUT) Cf[(size_t)r * N + col] = v;
          if (BF16OUT) Cb[(size_t)r * N + col] = f2bf(v);
          if (KV) {  // fused fp32 k/v export (qkv GEMM: cols 1024.. are k,v)
            if (col >= 2048)
              okv[(size_t)4096 * 1024 + (size_t)r * 1024 + (col - 2048)] = v;
            else if (col >= 1024)
              okv[(size_t)r * 1024 + (col - 1024)] = v;
          }
        }
      }
    }
  }
}

// out = res + p0 + p1 (split-K x2 reduce), f32x4 vectorized
__global__ __launch_bounds__(256) void k_red2(
    const f32x4* __restrict__ p, const f32x4* __restrict__ res,
    f32x4* __restrict__ out, int n) {
  size_t i = (size_t)blockIdx.x * 256 + threadIdx.x;
  out[i] = res[i] + (p[i] + p[i + (size_t)n]);
}

// ---------------------------------------------------------------------------
// Flash attention v4. 512 thr = 8 waves x 16 q-rows = 128 q/block.
// CAUSAL: grid (4,64), block handles supertiles {bx, 7-bx}; else grid (8,64).
// Swapped QK^T (lane holds S[q=la][k]); V pre-transposed; P via per-wave
// XOR-swizzled LDS scratch.
// ---------------------------------------------------------------------------
template <bool CAUSAL>
__global__ __launch_bounds__(512) void k_attn4(
    const short* __restrict__ qbuf, int qrs,
    const short* __restrict__ kbuf, int krs,
    const short* __restrict__ vT, int vts,
    short* __restrict__ obuf, int ors,
    const unsigned long long* __restrict__ mbits, int mwords,
    int Tq, int Tk, float scale) {
  __shared__ short Ks[64 * 64];
  __shared__ short Vs[64 * 64];
  __shared__ short Ps[8 * 1024];
  int bh = blockIdx.y, b = bh >> 4, h = bh & 15;
  int t = threadIdx.x, wid = t >> 6, lane = t & 63;
  int la = lane & 15, lb = lane >> 4;
  float lscale = scale * 1.44269504f;  // log2 domain

  const short* qB = qbuf + (size_t)b * Tq * qrs + h * 64;
  const short* kB = kbuf + (size_t)b * Tk * krs + h * 64;
  const short* vB = vT + (size_t)bh * 64 * vts;
  char* Pw = (char*)(Ps + wid * 1024);  // 16 rows x 128B per wave

  int sr = t >> 3, scol = (t & 7) * 8;
  int swz = sr * 64 + (scol ^ ((sr & 7) << 3));

  int nsup = CAUSAL ? 2 : 1;
  for (int s = 0; s < nsup; s++) {
    int st = CAUSAL ? (s ? 7 - blockIdx.x : blockIdx.x) : blockIdx.x;
    int q0 = st * 128 + wid * 16;
    int nkt = CAUSAL ? 2 * st + 2 : (Tk + 63) >> 6;
    int lastkt = CAUSAL ? (q0 >> 6) : nkt - 1;

    s8v qf[2];
#pragma unroll
    for (int kk = 0; kk < 2; kk++)
      qf[kk] = *(const s8v*)(qB + (size_t)(q0 + la) * qrs + kk * 32 + lb * 8);

    f32x4 accO[4];
#pragma unroll
    for (int n = 0; n < 4; n++) accO[n] = (f32x4){0.f, 0.f, 0.f, 0.f};
    float m = -1e30f, l = 0.f;

    s8v krg, vrg;
    {
      int tk = sr; if (tk > Tk - 1) tk = Tk - 1;
      krg = *(const s8v*)(kB + (size_t)tk * krs + scol);
      vrg = *(const s8v*)(vB + (size_t)sr * vts + scol);
    }

    for (int kt = 0; kt < nkt; kt++) {
      int kb0 = kt << 6;
      __syncthreads();
      *(s8v*)&Ks[swz] = krg;
      *(s8v*)&Vs[swz] = vrg;
      __syncthreads();
      if (kt + 1 < nkt) {
        int kb = kb0 + 64;
        int tk = kb + sr; if (tk > Tk - 1) tk = Tk - 1;
        krg = *(const s8v*)(kB + (size_t)tk * krs + scol);
        vrg = *(const s8v*)(vB + (size_t)sr * vts + kb + scol);
      }
      if (kt > lastkt) continue;  // fully-masked tile for this wave

      bool needMask;
      unsigned long long wm = ~0ull;
      if (CAUSAL) {
        needMask = (kt == lastkt);
      } else {
        wm = mbits[(size_t)b * mwords + kt];
        needMask = (wm != ~0ull);
      }

      float sc[4][4];
      __builtin_amdgcn_s_setprio(1);
#pragma unroll
      for (int n = 0; n < 4; n++) {
        f32x4 a = (f32x4){0.f, 0.f, 0.f, 0.f};
#pragma unroll
        for (int kk = 0; kk < 2; kk++) {
          s8v kf = *(const s8v*)&Ks[(n * 16 + la) * 64 +
                                    ((kk * 32 + lb * 8) ^ ((la & 7) << 3))];
          a = __builtin_amdgcn_mfma_f32_16x16x32_bf16(kf, qf[kk], a, 0, 0, 0);
        }
#pragma unroll
        for (int j = 0; j < 4; j++) {
          float sv = a[j] * lscale;
          if (needMask) {
            int ki = n * 16 + lb * 4 + j;
            bool ok = CAUSAL ? (kb0 + ki <= q0 + la) : (((wm >> ki) & 1ull) != 0);
            sv = ok ? sv : -1e30f;
          }
          sc[n][j] = sv;
        }
      }
      __builtin_amdgcn_s_setprio(0);

      float tm = sc[0][0];
#pragma unroll
      for (int n = 0; n < 4; n++)
#pragma unroll
        for (int j = 0; j < 4; j++) tm = fmaxf(tm, sc[n][j]);
      tm = fmaxf(tm, __shfl_xor(tm, 16));
      tm = fmaxf(tm, __shfl_xor(tm, 32));
      tm = fmaxf(tm, -1e4f);  // floor: masked rows decay to p=0 naturally

      bool skip = __all(tm - m <= 10.f);  // defer-max (T13)
      float alpha = 1.f;
      if (!skip) {
        float mn_ = fmaxf(m, tm);
        alpha = fexp2(m - mn_);
        m = mn_;
      }

      unsigned W[4][2];
      float ps = 0.f;
#pragma unroll
      for (int n = 0; n < 4; n++) {
        float p0 = fexp2(sc[n][0] - m), p1 = fexp2(sc[n][1] - m);
        float p2 = fexp2(sc[n][2] - m), p3 = fexp2(sc[n][3] - m);
        ps += (p0 + p1) + (p2 + p3);
        W[n][0] = cvtpk_bf2(p0, p1);
        W[n][1] = cvtpk_bf2(p2, p3);
      }
      ps += __shfl_xor(ps, 16);
      ps += __shfl_xor(ps, 32);
      l = l * alpha + ps;

      if (!skip) {
#pragma unroll
        for (int j = 0; j < 4; j++) {
          float aj = bpermf(lb * 20 + j, alpha);
#pragma unroll
          for (int n = 0; n < 4; n++) accO[n][j] *= aj;
        }
      }

      // P -> per-wave LDS scratch (swizzled), then PV
#pragma unroll
      for (int n = 0; n < 4; n++) {
        uint2v w2 = {W[n][0], W[n][1]};
        *(uint2v*)(Pw + ((la * 128 + n * 32 + lb * 8) ^ ((la & 7) << 4))) = w2;
      }
      __builtin_amdgcn_s_setprio(1);
#pragma unroll
      for (int kk = 0; kk < 2; kk++) {
        s8v pa = *(const s8v*)(Pw + ((la * 128 + kk * 64 + lb * 16) ^ ((la & 7) << 4)));
#pragma unroll
        for (int n = 0; n < 4; n++) {
          s8v vf = *(const s8v*)&Vs[(n * 16 + la) * 64 +
                                    ((kk * 32 + lb * 8) ^ ((la & 7) << 3))];
          accO[n] = __builtin_amdgcn_mfma_f32_16x16x32_bf16(pa, vf, accO[n], 0, 0, 0);
        }
      }
      __builtin_amdgcn_s_setprio(0);
    }

#pragma unroll
    for (int j = 0; j < 4; j++) {
      float lj = bpermf(lb * 20 + j, l);
      float inv = 1.f / lj;
      int r = q0 + lb * 4 + j;
#pragma unroll
      for (int n = 0; n < 4; n++)
        obuf[(size_t)(b * Tq + r) * ors + h * 64 + n * 16 + la] = f2bf(accO[n][j] * inv);
    }
  }
}

// ---------------------------------------------------------------------------
extern "C" void kernel_launch(void* const* d_in, const int* in_sizes, int n_in,
                              void* d_out, int out_size, void* d_ws, size_t ws_size,
                              hipStream_t stream) {
  (void)in_sizes; (void)n_in; (void)out_size; (void)ws_size;
  const float* x      = (const float*)d_in[0];
  const float* enc    = (const float*)d_in[1];
  const int*   mask   = (const int*)d_in[2];
  const float* w_qkv  = (const float*)d_in[3];
  const float* w_o_sa = (const float*)d_in[4];
  const float* w_q    = (const float*)d_in[5];
  const float* w_kv   = (const float*)d_in[6];
  const float* w_o_xa = (const float*)d_in[7];
  const float* w_ff1  = (const float*)d_in[8];
  const float* w_ff2  = (const float*)d_in[9];
  const float* g_sa   = (const float*)d_in[10];
  const float* g_xaq  = (const float*)d_in[11];
  const float* g_xam  = (const float*)d_in[12];
  const float* g_ff   = (const float*)d_in[13];

  float* out_x = (float*)d_out;
  float* out_k = out_x + (size_t)4096 * 1024;

  char* ws = (char*)d_ws;
  size_t off = 0;
  auto alloc = [&](size_t bytes) -> void* {
    void* p = ws + off;
    off += (bytes + 255) & ~(size_t)255;
    return p;
  };
  short* wqkv_t = (short*)alloc((size_t)3072 * 1024 * 2);
  short* wosa_t = (short*)alloc((size_t)1024 * 1024 * 2);
  short* wq_t   = (short*)alloc((size_t)1024 * 1024 * 2);
  short* wkv_t  = (short*)alloc((size_t)2048 * 1024 * 2);
  short* woxa_t = (short*)alloc((size_t)1024 * 1024 * 2);
  short* wff1_t = (short*)alloc((size_t)4096 * 1024 * 2);
  short* wff2_t = (short*)alloc((size_t)1024 * 4096 * 2);
  short* xn     = (short*)alloc((size_t)4096 * 1024 * 2);  // reused as vTsa
  short* qkv_b  = (short*)alloc((size_t)4096 * 3072 * 2);  // + ff2 partial slab
  short* sa_b   = (short*)alloc((size_t)4096 * 1024 * 2);  //   (part spans both)
  float* x1     = (float*)alloc((size_t)4096 * 1024 * 4);
  short* qn     = (short*)alloc((size_t)4096 * 1024 * 2);
  short* mn     = (short*)alloc((size_t)6000 * 1024 * 2);
  short* qx_b   = (short*)alloc((size_t)4096 * 1024 * 2);
  short* kvx_b  = (short*)alloc((size_t)6000 * 2048 * 2);
  short* xa_b   = (short*)alloc((size_t)4096 * 1024 * 2);
  float* x2     = (float*)alloc((size_t)4096 * 1024 * 4);
  short* hn     = (short*)alloc((size_t)4096 * 1024 * 2);
  short* h1     = (short*)alloc((size_t)4096 * 4096 * 2);  // first 12.6MB reused as vTxa
  unsigned long long* mbits = (unsigned long long*)alloc(4 * 24 * 8);

  short* vTsa = xn;            // [64 bh][64][1024]
  short* vTxa = h1;            // [64 bh][64][1536]
  float* part = (float*)qkv_b; // 32MB split-K partials (qkv_b+sa_b, dead by ff2)

  // weights -> bf16 transposed
  k_transpose_cvt<<<dim3(96, 32), 256, 0, stream>>>(w_qkv, wqkv_t, 1024, 3072);
  k_transpose_cvt<<<dim3(32, 32), 256, 0, stream>>>(w_o_sa, wosa_t, 1024, 1024);
  k_transpose_cvt<<<dim3(32, 32), 256, 0, stream>>>(w_q, wq_t, 1024, 1024);
  k_transpose_cvt<<<dim3(64, 32), 256, 0, stream>>>(w_kv, wkv_t, 1024, 2048);
  k_transpose_cvt<<<dim3(32, 32), 256, 0, stream>>>(w_o_xa, woxa_t, 1024, 1024);
  k_transpose_cvt<<<dim3(128, 32), 256, 0, stream>>>(w_ff1, wff1_t, 1024, 4096);
  k_transpose_cvt<<<dim3(32, 128), 256, 0, stream>>>(w_ff2, wff2_t, 4096, 1024);
  k_maskpack<<<4, 64, 0, stream>>>(mask, mbits, 1500, 24);

  // --- self-attention block ---
  k_ln<<<4096, 256, 0, stream>>>(x, g_sa, xn);
  k_gemm<false, false, false, true, true><<<dim3(32, 24), 256, 0, stream>>>(
      xn, wqkv_t, nullptr, qkv_b, nullptr, out_k, 4096, 3072, 1024, 1024, 1024);
  k_vtrans<<<dim3(32, 64), 256, 0, stream>>>(qkv_b, 3072, 2048, vTsa, 1024, 1024);
  k_attn4<true><<<dim3(4, 64), 512, 0, stream>>>(
      qkv_b, 3072, qkv_b + 1024, 3072, vTsa, 1024,
      sa_b, 1024, nullptr, 0, 1024, 1024, 0.125f);
  k_gemm<true, false, true, false, false><<<dim3(32, 8), 256, 0, stream>>>(
      sa_b, wosa_t, x1, nullptr, x, nullptr, 4096, 1024, 1024, 1024, 1024);

  // --- cross-attention block ---
  k_ln<<<4096, 256, 0, stream>>>(x1, g_xaq, qn);
  k_ln<<<6000, 256, 0, stream>>>(enc, g_xam, mn);
  k_gemm<false, false, false, true, false><<<dim3(32, 8), 256, 0, stream>>>(
      qn, wq_t, nullptr, qx_b, nullptr, nullptr, 4096, 1024, 1024, 1024, 1024);
  k_gemm<false, false, false, true, false><<<dim3(47, 16), 256, 0, stream>>>(
      mn, wkv_t, nullptr, kvx_b, nullptr, nullptr, 6000, 2048, 1024, 1024, 1024);
  k_vtrans<<<dim3(48, 64), 256, 0, stream>>>(kvx_b, 2048, 1024, vTxa, 1500, 1536);
  k_attn4<false><<<dim3(8, 64), 512, 0, stream>>>(
      qx_b, 1024, kvx_b, 2048, vTxa, 1536,
      xa_b, 1024, mbits, 24, 1024, 1500, 0.125f);
  k_gemm<true, false, true, false, false><<<dim3(32, 8), 256, 0, stream>>>(
      xa_b, woxa_t, x2, nullptr, x1, nullptr, 4096, 1024, 1024, 1024, 1024);

  // --- FFN block ---
  k_ln<<<4096, 256, 0, stream>>>(x2, g_ff, hn);
  k_gemm<false, true, false, true, false><<<dim3(32, 32), 256, 0, stream>>>(
      hn, wff1_t, nullptr, h1, nullptr, nullptr, 4096, 4096, 1024, 1024, 1024);
  // ff2: split-K x2 (K=2048 each), fp32 partials + reduce(+residual)
  k_gemm<false, false, true, false, false><<<dim3(32, 8, 2), 256, 0, stream>>>(
      h1, wff2_t, part, nullptr, nullptr, nullptr, 4096, 1024, 2048, 4096, 4096);
  k_red2<<<4096, 256, 0, stream>>>(
      (const f32x4*)part, (const f32x4*)x2, (f32x4*)out_x, 1048576);
}